// Round 7
// baseline (2587.809 us; speedup 1.0000x reference)
//
// Round 7: stage all MLP weights (43.1 KB) in LDS. Round-6 counters showed
// VALUBusy=44%, occ=22.5%, SGPR=112: scalar-path weight loads thrash the
// ~16KB K$ (42KB working set) -> lgkm stalls. LDS broadcast reads fix latency.
#include <hip/hip_runtime.h>

#define PI_F     3.14159265358979323846f
#define TWO_PI_F 6.28318530717958647692f

__device__ __forceinline__ float fast_rcp(float x) { return __builtin_amdgcn_rcpf(x); }

__device__ __forceinline__ float silu_f(float v) {
    return v * fast_rcp(1.0f + __expf(-v));   // v * sigmoid(v)
}

__device__ __forceinline__ float tanh_f(float z) {
    float ez = __expf(2.0f * z);
    return 1.0f - 2.0f * fast_rcp(ez + 1.0f);
}

// LDS layout offsets (floats)
#define OFF_WR1 0
#define OFF_BR1 896
#define OFF_WR2 960
#define OFF_BR2 5056
#define OFF_WR3 5120
#define OFF_BR3 5376
#define OFF_WI1 5380
#define OFF_BI1 6276
#define OFF_WI2 6340
#define OFF_BI2 10436
#define OFF_WI3 10500
#define OFF_BI3 10756
#define OFF_WA  10760
#define OFF_BA  10784
#define SM_TOTAL 10787

// MLP 14 -> 64 -> 64 -> 4, silu on first two layers; weights from LDS
// (wave-uniform broadcast ds_reads, contiguous in j => ds_read_b128).
__device__ __forceinline__ void mlp14_64_64_4(
    const float x[14],
    const float* __restrict__ W1, const float* __restrict__ b1,
    const float* __restrict__ W2, const float* __restrict__ b2,
    const float* __restrict__ W3, const float* __restrict__ b3,
    float A[4])
{
    float h1[64];
    #pragma unroll
    for (int j = 0; j < 64; ++j) h1[j] = b1[j];
    #pragma unroll
    for (int k = 0; k < 14; ++k) {
        const float xk = x[k];
        #pragma unroll
        for (int j = 0; j < 64; ++j) h1[j] += xk * W1[k * 64 + j];
    }
    #pragma unroll
    for (int j = 0; j < 64; ++j) h1[j] = silu_f(h1[j]);

    float h2[64];
    #pragma unroll
    for (int j = 0; j < 64; ++j) h2[j] = b2[j];
    #pragma unroll
    for (int k = 0; k < 64; ++k) {
        const float hk = h1[k];
        #pragma unroll
        for (int j = 0; j < 64; ++j) h2[j] += hk * W2[k * 64 + j];
    }
    #pragma unroll
    for (int j = 0; j < 64; ++j) h2[j] = silu_f(h2[j]);

    float a0 = b3[0], a1 = b3[1], a2 = b3[2], a3 = b3[3];
    #pragma unroll
    for (int k = 0; k < 64; ++k) {
        const float hk = h2[k];
        a0 += hk * W3[k * 4 + 0];
        a1 += hk * W3[k * 4 + 1];
        a2 += hk * W3[k * 4 + 2];
        a3 += hk * W3[k * 4 + 3];
    }
    A[0] = a0; A[1] = a1; A[2] = a2; A[3] = a3;
}

__global__ __launch_bounds__(256) void qgnn_zero_kernel(float* __restrict__ p, int n) {
    const int i = blockIdx.x * blockDim.x + threadIdx.x;
    if (i < n) p[i] = 0.0f;
}

template<int STRIDE>
__global__ __launch_bounds__(256) void qgnn_edge_kernel(
    const float* __restrict__ hr,   // (N,2,2) flat
    const float* __restrict__ hi,   // (N,2,2) flat
    const int*   __restrict__ ei,   // (2,E) flat
    const float* __restrict__ npar, // (N,2)
    const float* __restrict__ epar, // (N,1)
    const float* __restrict__ Wa, const float* __restrict__ ba,
    const float* __restrict__ Wr1, const float* __restrict__ br1,
    const float* __restrict__ Wr2, const float* __restrict__ br2,
    const float* __restrict__ Wr3, const float* __restrict__ br3,
    const float* __restrict__ Wi1, const float* __restrict__ bi1,
    const float* __restrict__ Wi2, const float* __restrict__ bi2,
    const float* __restrict__ Wi3, const float* __restrict__ bi3,
    float* __restrict__ aggout,     // agg[n][t] at aggout[STRIDE*n+t], t<3
    int E)
{
    __shared__ float sm[SM_TOTAL];

    // Cooperative weight staging (all threads participate before any exit).
    const int tid = threadIdx.x;
    #define STAGE(OFF, SRC, CNT) \
        for (int i = tid; i < (CNT); i += 256) sm[(OFF) + i] = SRC[i];
    STAGE(OFF_WR1, Wr1, 896)  STAGE(OFF_BR1, br1, 64)
    STAGE(OFF_WR2, Wr2, 4096) STAGE(OFF_BR2, br2, 64)
    STAGE(OFF_WR3, Wr3, 256)  STAGE(OFF_BR3, br3, 4)
    STAGE(OFF_WI1, Wi1, 896)  STAGE(OFF_BI1, bi1, 64)
    STAGE(OFF_WI2, Wi2, 4096) STAGE(OFF_BI2, bi2, 64)
    STAGE(OFF_WI3, Wi3, 256)  STAGE(OFF_BI3, bi3, 4)
    STAGE(OFF_WA,  Wa,  24)   STAGE(OFF_BA,  ba,  3)
    #undef STAGE
    __syncthreads();

    const int e = blockIdx.x * blockDim.x + tid;
    if (e >= E) return;

    const int s = ei[e];
    const int r = ei[E + e];

    // ep gather: edge_params[edge_index].reshape(E,2) row-major flatten
    // => ep[e] = (P[ei_flat[2e]], P[ei_flat[2e+1]])
    const float ep0 = epar[ei[2 * e + 0]];
    const float ep1 = epar[ei[2 * e + 1]];

    const float4 hrs = *reinterpret_cast<const float4*>(hr + 4 * (size_t)s);
    const float4 hrr = *reinterpret_cast<const float4*>(hr + 4 * (size_t)r);
    const float2 nps = *reinterpret_cast<const float2*>(npar + 2 * (size_t)s);
    const float2 npr = *reinterpret_cast<const float2*>(npar + 2 * (size_t)r);

    float x[14];
    x[0] = hrs.x; x[1] = hrs.y; x[2] = hrs.z; x[3] = hrs.w;
    x[4] = hrr.x; x[5] = hrr.y; x[6] = hrr.z; x[7] = hrr.w;
    x[8] = nps.x; x[9] = nps.y; x[10] = npr.x; x[11] = npr.y;
    x[12] = ep0;  x[13] = ep1;

    float Ar[4];
    mlp14_64_64_4(x, sm + OFF_WR1, sm + OFF_BR1, sm + OFF_WR2, sm + OFF_BR2,
                  sm + OFF_WR3, sm + OFF_BR3, Ar);

    const float4 his = *reinterpret_cast<const float4*>(hi + 4 * (size_t)s);
    const float4 hir = *reinterpret_cast<const float4*>(hi + 4 * (size_t)r);
    x[0] = his.x; x[1] = his.y; x[2] = his.z; x[3] = his.w;
    x[4] = hir.x; x[5] = hir.y; x[6] = hir.z; x[7] = hir.w;

    float Ai[4];
    mlp14_64_64_4(x, sm + OFF_WI1, sm + OFF_BI1, sm + OFF_WI2, sm + OFF_BI2,
                  sm + OFF_WI3, sm + OFF_BI3, Ai);

    // angles = tanh(concat([A_imag, A_real]) @ Wa + ba); m_ij = angles * pi
    #pragma unroll
    for (int t = 0; t < 3; ++t) {
        float z = sm[OFF_BA + t];
        #pragma unroll
        for (int j = 0; j < 4; ++j) z += Ai[j] * sm[OFF_WA + j * 3 + t];
        #pragma unroll
        for (int j = 0; j < 4; ++j) z += Ar[j] * sm[OFF_WA + (4 + j) * 3 + t];
        const float m = tanh_f(z) * PI_F;
        atomicAdd(aggout + (size_t)STRIDE * (size_t)r + t, m);
    }
}

__device__ __forceinline__ float wrap_pi(float v) {
    // jnp: (v + pi) % (2*pi) - pi, with % returning non-negative remainder
    float rm = fmodf(v + PI_F, TWO_PI_F);
    if (rm < 0.0f) rm += TWO_PI_F;
    return rm - PI_F;
}

template<int STRIDE, bool WRITE_COMPLEX>
__global__ __launch_bounds__(256) void qgnn_node_kernel(
    const float* __restrict__ hr,
    const float* __restrict__ hi,
    float* __restrict__ out,   // reads agg from [STRIDE*n .. +2], overwrites own slot
    int N)
{
    const int n = blockIdx.x * blockDim.x + threadIdx.x;
    if (n >= N) return;

    const float a = wrap_pi(out[(size_t)STRIDE * n + 0]);
    const float b = wrap_pi(out[(size_t)STRIDE * n + 1]);
    const float c = wrap_pi(out[(size_t)STRIDE * n + 2]);

    const float cb = __cosf(0.5f * b);
    const float sb = __sinf(0.5f * b);
    const float hpc = 0.5f * (a + c);
    const float hmc = 0.5f * (a - c);
    const float cpc = __cosf(hpc), spc = __sinf(hpc);
    const float cmc = __cosf(hmc), smc = __sinf(hmc);

    float Ur[2][2], Ui[2][2];
    Ur[0][0] =  cpc * cb;  Ui[0][0] = -spc * cb;
    Ur[0][1] = -cmc * sb;  Ui[0][1] =  smc * sb;
    Ur[1][0] =  cmc * sb;  Ui[1][0] =  smc * sb;
    Ur[1][1] =  cpc * cb;  Ui[1][1] =  spc * cb;

    const float4 h4r = *reinterpret_cast<const float4*>(hr + 4 * (size_t)n);
    const float4 h4i = *reinterpret_cast<const float4*>(hi + 4 * (size_t)n);
    float Hr[2][2] = {{h4r.x, h4r.y}, {h4r.z, h4r.w}};
    float Hi[2][2] = {{h4i.x, h4i.y}, {h4i.z, h4i.w}};

    // T = H @ U^dagger : T[p][j] = sum_t H[p][t] * conj(U[j][t])
    float Tr[2][2], Ti[2][2];
    #pragma unroll
    for (int p = 0; p < 2; ++p) {
        #pragma unroll
        for (int j = 0; j < 2; ++j) {
            float tr = 0.0f, ti = 0.0f;
            #pragma unroll
            for (int t = 0; t < 2; ++t) {
                tr += Hr[p][t] * Ur[j][t] + Hi[p][t] * Ui[j][t];
                ti += Hi[p][t] * Ur[j][t] - Hr[p][t] * Ui[j][t];
            }
            Tr[p][j] = tr; Ti[p][j] = ti;
        }
    }

    // out = U @ T
    float orr[2][2], oii[2][2];
    #pragma unroll
    for (int i = 0; i < 2; ++i) {
        #pragma unroll
        for (int j = 0; j < 2; ++j) {
            float xr = 0.0f, xi = 0.0f;
            #pragma unroll
            for (int p = 0; p < 2; ++p) {
                xr += Ur[i][p] * Tr[p][j] - Ui[i][p] * Ti[p][j];
                xi += Ur[i][p] * Ti[p][j] + Ui[i][p] * Tr[p][j];
            }
            orr[i][j] = xr; oii[i][j] = xi;
        }
    }

    if (WRITE_COMPLEX) {
        float4* outv = reinterpret_cast<float4*>(out + (size_t)STRIDE * n);
        outv[0] = make_float4(orr[0][0], oii[0][0], orr[0][1], oii[0][1]);
        outv[1] = make_float4(orr[1][0], oii[1][0], orr[1][1], oii[1][1]);
    } else {
        // real part only, row-major (n,2,2)
        *reinterpret_cast<float4*>(out + (size_t)STRIDE * n) =
            make_float4(orr[0][0], orr[0][1], orr[1][0], orr[1][1]);
    }
}

extern "C" void kernel_launch(void* const* d_in, const int* in_sizes, int n_in,
                              void* d_out, int out_size, void* d_ws, size_t ws_size,
                              hipStream_t stream) {
    const float* hr   = (const float*)d_in[0];
    const float* hi   = (const float*)d_in[1];
    const int*   ei   = (const int*)  d_in[2];
    const float* npar = (const float*)d_in[3];
    const float* epar = (const float*)d_in[4];
    const float* Wa  = (const float*)d_in[5];
    const float* ba  = (const float*)d_in[6];
    const float* Wr1 = (const float*)d_in[7];
    const float* br1 = (const float*)d_in[8];
    const float* Wr2 = (const float*)d_in[9];
    const float* br2 = (const float*)d_in[10];
    const float* Wr3 = (const float*)d_in[11];
    const float* br3 = (const float*)d_in[12];
    const float* Wi1 = (const float*)d_in[13];
    const float* bi1 = (const float*)d_in[14];
    const float* Wi2 = (const float*)d_in[15];
    const float* bi2 = (const float*)d_in[16];
    const float* Wi3 = (const float*)d_in[17];
    const float* bi3 = (const float*)d_in[18];

    const int N = in_sizes[0] / 4;   // h_i_real is (N,2,2)
    const int E = in_sizes[2] / 2;   // edge_index is (2,E)

    float* out = (float*)d_out;
    const bool cplx = (out_size >= 8 * N);   // 8 floats/node (complex64) vs 4 (real)

    const int total = cplx ? 8 * N : 4 * N;
    qgnn_zero_kernel<<<(total + 255) / 256, 256, 0, stream>>>(out, total);

    if (cplx) {
        qgnn_edge_kernel<8><<<(E + 255) / 256, 256, 0, stream>>>(
            hr, hi, ei, npar, epar, Wa, ba,
            Wr1, br1, Wr2, br2, Wr3, br3,
            Wi1, bi1, Wi2, bi2, Wi3, bi3, out, E);
        qgnn_node_kernel<8, true><<<(N + 255) / 256, 256, 0, stream>>>(hr, hi, out, N);
    } else {
        qgnn_edge_kernel<4><<<(E + 255) / 256, 256, 0, stream>>>(
            hr, hi, ei, npar, epar, Wa, ba,
            Wr1, br1, Wr2, br2, Wr3, br3,
            Wi1, bi1, Wi2, bi2, Wi3, bi3, out, E);
        qgnn_node_kernel<4, false><<<(N + 255) / 256, 256, 0, stream>>>(hr, hi, out, N);
    }
}

// Round 8
// 544.471 us; speedup vs baseline: 4.7529x; 4.7529x over previous
//
// Round 8: MFMA rewrite. Edge MLPs = batched GEMM -> mfma_f32_16x16x32_bf16
// with split-bf16 (hi+lo, 3 MFMAs per GEMM) for fp32-equivalent accuracy.
// Weights pre-fragmented into d_ws by a prep kernel (ws_size-guarded;
// falls back to the round-6 scalar kernel if scratch is too small).
#include <hip/hip_runtime.h>

#define PI_F     3.14159265358979323846f
#define TWO_PI_F 6.28318530717958647692f

typedef __attribute__((ext_vector_type(8))) short short8;
typedef __attribute__((ext_vector_type(4))) float f32x4;

__device__ __forceinline__ float fast_rcp(float x) { return __builtin_amdgcn_rcpf(x); }
__device__ __forceinline__ float silu_f(float v) { return v * fast_rcp(1.0f + __expf(-v)); }
__device__ __forceinline__ float tanh_f(float z) {
    float ez = __expf(2.0f * z);
    return 1.0f - 2.0f * fast_rcp(ez + 1.0f);
}

// bf16 round-to-nearest-even split helpers
__device__ __forceinline__ unsigned short f2bf(float f) {
    unsigned u = __float_as_uint(f);
    u += 0x7FFFu + ((u >> 16) & 1u);
    return (unsigned short)(u >> 16);
}
__device__ __forceinline__ float bf2f(unsigned short h) {
    return __uint_as_float(((unsigned)h) << 16);
}

// ---------------- prep: fragment-ordered bf16 hi/lo weight planes ----------
// Layout per MLP (u16 elems): L1 [0,2048) KT=1 NT=4; L2 [2048,6144) KT=2 NT=4;
// L3 [6144,7168) KT=2 NT=1. MLP r at 0, MLP i at +7168. hi plane [0,14336),
// lo plane [14336,28672). Frag elem: ((kt*NT+nt)*64 + lane)*8 + j holds
// W[kt*32 + 8*(lane>>4)+j][nt*16 + (lane&15)] (zero-padded).
#define WS_U16_TOTAL 28672
#define WS_BYTES_NEEDED (WS_U16_TOTAL * 2)

__global__ __launch_bounds__(256) void qgnn_prep_kernel(
    const float* __restrict__ Wr1, const float* __restrict__ Wr2, const float* __restrict__ Wr3,
    const float* __restrict__ Wi1, const float* __restrict__ Wi2, const float* __restrict__ Wi3,
    unsigned short* __restrict__ wsu)
{
    int idx = blockIdx.x * 256 + threadIdx.x;
    if (idx >= 14336) return;
    int rel = idx;
    int half = (rel >= 7168);
    if (half) rel -= 7168;
    const float* W; int base, NT, Kr, Nr;
    if (rel < 2048)      { W = half ? Wi1 : Wr1; base = 0;    NT = 4; Kr = 14; Nr = 64; }
    else if (rel < 6144) { W = half ? Wi2 : Wr2; base = 2048; NT = 4; Kr = 64; Nr = 64; }
    else                 { W = half ? Wi3 : Wr3; base = 6144; NT = 1; Kr = 64; Nr = 4;  }
    int f = rel - base;
    int frag = f >> 9, rem = f & 511;
    int l = rem >> 3, j = rem & 7;
    int nt = frag % NT, kt = frag / NT;
    int k = kt * 32 + ((l >> 4) << 3) + j;
    int n = nt * 16 + (l & 15);
    float v = (k < Kr && n < Nr) ? W[k * Nr + n] : 0.0f;
    unsigned short hi = f2bf(v);
    unsigned short lo = f2bf(v - bf2f(hi));
    wsu[idx] = hi;
    wsu[14336 + idx] = lo;
}

__global__ __launch_bounds__(256) void qgnn_zero_kernel(float* __restrict__ p, int n) {
    const int i = blockIdx.x * blockDim.x + threadIdx.x;
    if (i < n) p[i] = 0.0f;
}

// ---------------- MFMA edge kernel ----------------
__device__ __forceinline__ void stageW(unsigned short* dst, const unsigned short* src, int cnt16) {
    for (int o = threadIdx.x * 8; o < cnt16; o += 256 * 8)
        *reinterpret_cast<uint4*>(dst + o) = *reinterpret_cast<const uint4*>(src + o);
}

#define MFMA(a, b, c) __builtin_amdgcn_mfma_f32_16x16x32_bf16((a), (b), (c), 0, 0, 0)

__global__ __launch_bounds__(256) void qgnn_edge_mfma_kernel(
    const float* __restrict__ hr, const float* __restrict__ hi_,
    const int* __restrict__ ei,
    const float* __restrict__ npar, const float* __restrict__ epar,
    const float* __restrict__ Wa, const float* __restrict__ ba,
    const float* __restrict__ br1, const float* __restrict__ br2, const float* __restrict__ br3,
    const float* __restrict__ bi1, const float* __restrict__ bi2, const float* __restrict__ bi3,
    const unsigned short* __restrict__ wsu,
    float* __restrict__ aggout, int E, int stride)
{
    __shared__ __align__(16) unsigned short sXh[2][64 * 40];
    __shared__ __align__(16) unsigned short sXl[2][64 * 40];
    __shared__ __align__(16) unsigned short sHh[64 * 72];
    __shared__ __align__(16) unsigned short sHl[64 * 72];
    __shared__ __align__(16) unsigned short sWh[4096];
    __shared__ __align__(16) unsigned short sWl[4096];
    __shared__ __align__(16) float sH3[64 * 8];

    const int tid  = threadIdx.x;
    const int base = blockIdx.x * 64;

    // ---- gather: build X tiles [64 edges][40 pad] hi/lo (k>=14 zeroed) ----
    {
        const int el = tid & 63, q = tid >> 6;
        const int e = base + el;
        const bool valid = (e < E);
        unsigned short* Xh = sXh[q >> 1];
        unsigned short* Xl = sXl[q >> 1];
        float v[8];
        int f0, cnt;
        if ((q & 1) == 0) {
            f0 = 0; cnt = 8;
            float4 a = make_float4(0.f, 0.f, 0.f, 0.f), b = a;
            if (valid) {
                const float* hsrc = (q >= 2) ? hi_ : hr;
                const int s = ei[e], r = ei[E + e];
                a = *reinterpret_cast<const float4*>(hsrc + 4 * (size_t)s);
                b = *reinterpret_cast<const float4*>(hsrc + 4 * (size_t)r);
            }
            v[0] = a.x; v[1] = a.y; v[2] = a.z; v[3] = a.w;
            v[4] = b.x; v[5] = b.y; v[6] = b.z; v[7] = b.w;
        } else {
            f0 = 8; cnt = 6;
            float2 nps = make_float2(0.f, 0.f), npr = nps;
            float e0 = 0.f, e1 = 0.f;
            if (valid) {
                const int s = ei[e], r = ei[E + e];
                nps = *reinterpret_cast<const float2*>(npar + 2 * (size_t)s);
                npr = *reinterpret_cast<const float2*>(npar + 2 * (size_t)r);
                e0 = epar[ei[2 * e + 0]];
                e1 = epar[ei[2 * e + 1]];
            }
            v[0] = nps.x; v[1] = nps.y; v[2] = npr.x; v[3] = npr.y; v[4] = e0; v[5] = e1;
        }
        for (int t = 0; t < cnt; ++t) {
            unsigned short h = f2bf(v[t]);
            Xh[el * 40 + f0 + t] = h;
            Xl[el * 40 + f0 + t] = f2bf(v[t] - bf2f(h));
        }
        if (q & 1) {
            for (int f = 14; f < 32; ++f) { Xh[el * 40 + f] = 0; Xl[el * 40 + f] = 0; }
        }
    }
    __syncthreads();

    const int lane = tid & 63, w = tid >> 6;
    const int m16 = lane & 15, g = lane >> 4;
    const int arow = 16 * w + m16;

    #pragma unroll 1
    for (int mlp = 0; mlp < 2; ++mlp) {
        const unsigned short* wh = wsu + mlp * 7168;
        const unsigned short* wl = wsu + 14336 + mlp * 7168;
        const float* b1 = mlp ? bi1 : br1;
        const float* b2 = mlp ? bi2 : br2;
        const float* b3 = mlp ? bi3 : br3;
        const unsigned short* Xh = sXh[mlp];
        const unsigned short* Xl = sXl[mlp];

        // ---------- Layer 1: (16x32) @ (32x64) ----------
        stageW(sWh, wh + 0, 2048);
        stageW(sWl, wl + 0, 2048);
        __syncthreads();
        {
            const short8 ah = *reinterpret_cast<const short8*>(&Xh[arow * 40 + 8 * g]);
            const short8 al = *reinterpret_cast<const short8*>(&Xl[arow * 40 + 8 * g]);
            #pragma unroll
            for (int nt = 0; nt < 4; ++nt) {
                const float bv = b1[nt * 16 + m16];
                f32x4 acc = {bv, bv, bv, bv};
                const short8 bh = *reinterpret_cast<const short8*>(&sWh[(nt * 64 + lane) * 8]);
                const short8 bl = *reinterpret_cast<const short8*>(&sWl[(nt * 64 + lane) * 8]);
                acc = MFMA(al, bh, acc);
                acc = MFMA(ah, bl, acc);
                acc = MFMA(ah, bh, acc);
                #pragma unroll
                for (int i = 0; i < 4; ++i) {
                    const float hv = silu_f(acc[i]);
                    const int row = 16 * w + 4 * g + i;
                    const int col = nt * 16 + m16;
                    const unsigned short hh = f2bf(hv);
                    sHh[row * 72 + col] = hh;
                    sHl[row * 72 + col] = f2bf(hv - bf2f(hh));
                }
            }
        }
        __syncthreads();

        // ---------- Layer 2: (16x64) @ (64x64) ----------
        stageW(sWh, wh + 2048, 4096);
        stageW(sWl, wl + 2048, 4096);
        __syncthreads();
        {
            const short8 a0h = *reinterpret_cast<const short8*>(&sHh[arow * 72 + 8 * g]);
            const short8 a0l = *reinterpret_cast<const short8*>(&sHl[arow * 72 + 8 * g]);
            const short8 a1h = *reinterpret_cast<const short8*>(&sHh[arow * 72 + 32 + 8 * g]);
            const short8 a1l = *reinterpret_cast<const short8*>(&sHl[arow * 72 + 32 + 8 * g]);
            #pragma unroll
            for (int nt = 0; nt < 4; ++nt) {
                const float bv = b2[nt * 16 + m16];
                f32x4 acc = {bv, bv, bv, bv};
                const short8 bh0 = *reinterpret_cast<const short8*>(&sWh[((0 * 4 + nt) * 64 + lane) * 8]);
                const short8 bl0 = *reinterpret_cast<const short8*>(&sWl[((0 * 4 + nt) * 64 + lane) * 8]);
                const short8 bh1 = *reinterpret_cast<const short8*>(&sWh[((1 * 4 + nt) * 64 + lane) * 8]);
                const short8 bl1 = *reinterpret_cast<const short8*>(&sWl[((1 * 4 + nt) * 64 + lane) * 8]);
                acc = MFMA(a0l, bh0, acc);
                acc = MFMA(a0h, bl0, acc);
                acc = MFMA(a0h, bh0, acc);
                acc = MFMA(a1l, bh1, acc);
                acc = MFMA(a1h, bl1, acc);
                acc = MFMA(a1h, bh1, acc);
                #pragma unroll
                for (int i = 0; i < 4; ++i) {
                    const float hv = silu_f(acc[i]);
                    const int row = 16 * w + 4 * g + i;
                    const int col = nt * 16 + m16;
                    const unsigned short hh = f2bf(hv);
                    sHh[row * 72 + col] = hh;
                    sHl[row * 72 + col] = f2bf(hv - bf2f(hh));
                }
            }
        }
        __syncthreads();

        // ---------- Layer 3: (16x64) @ (64x16), 4 valid cols ----------
        stageW(sWh, wh + 6144, 1024);
        stageW(sWl, wl + 6144, 1024);
        __syncthreads();
        {
            const short8 a0h = *reinterpret_cast<const short8*>(&sHh[arow * 72 + 8 * g]);
            const short8 a0l = *reinterpret_cast<const short8*>(&sHl[arow * 72 + 8 * g]);
            const short8 a1h = *reinterpret_cast<const short8*>(&sHh[arow * 72 + 32 + 8 * g]);
            const short8 a1l = *reinterpret_cast<const short8*>(&sHl[arow * 72 + 32 + 8 * g]);
            const float bv = (m16 < 4) ? b3[m16] : 0.0f;
            f32x4 acc = {bv, bv, bv, bv};
            const short8 bh0 = *reinterpret_cast<const short8*>(&sWh[(0 * 64 + lane) * 8]);
            const short8 bl0 = *reinterpret_cast<const short8*>(&sWl[(0 * 64 + lane) * 8]);
            const short8 bh1 = *reinterpret_cast<const short8*>(&sWh[(1 * 64 + lane) * 8]);
            const short8 bl1 = *reinterpret_cast<const short8*>(&sWl[(1 * 64 + lane) * 8]);
            acc = MFMA(a0l, bh0, acc);
            acc = MFMA(a0h, bl0, acc);
            acc = MFMA(a0h, bh0, acc);
            acc = MFMA(a1l, bh1, acc);
            acc = MFMA(a1h, bl1, acc);
            acc = MFMA(a1h, bh1, acc);
            if (m16 < 4) {
                #pragma unroll
                for (int i = 0; i < 4; ++i)
                    sH3[(16 * w + 4 * g + i) * 8 + m16 + 4 * mlp] = acc[i];
            }
        }
        __syncthreads();
    }

    // ---- epilogue: angles -> tanh -> atomic segment-sum ----
    if (tid < 64) {
        const int e = base + tid;
        if (e < E) {
            float Ar[4], Ai[4];
            #pragma unroll
            for (int j = 0; j < 4; ++j) { Ar[j] = sH3[tid * 8 + j]; Ai[j] = sH3[tid * 8 + 4 + j]; }
            const int r = ei[E + e];
            #pragma unroll
            for (int t = 0; t < 3; ++t) {
                float z = ba[t];
                #pragma unroll
                for (int j = 0; j < 4; ++j) z += Ai[j] * Wa[j * 3 + t];
                #pragma unroll
                for (int j = 0; j < 4; ++j) z += Ar[j] * Wa[(4 + j) * 3 + t];
                atomicAdd(aggout + (size_t)stride * (size_t)r + t, tanh_f(z) * PI_F);
            }
        }
    }
}

// ---------------- round-6 scalar fallback (ws too small) ----------------
__device__ __forceinline__ void mlp14_64_64_4(
    const float x[14],
    const float* __restrict__ W1, const float* __restrict__ b1,
    const float* __restrict__ W2, const float* __restrict__ b2,
    const float* __restrict__ W3, const float* __restrict__ b3,
    float A[4])
{
    float h1[64];
    #pragma unroll
    for (int j = 0; j < 64; ++j) h1[j] = b1[j];
    #pragma unroll
    for (int k = 0; k < 14; ++k) {
        const float xk = x[k];
        #pragma unroll
        for (int j = 0; j < 64; ++j) h1[j] += xk * W1[k * 64 + j];
    }
    #pragma unroll
    for (int j = 0; j < 64; ++j) h1[j] = silu_f(h1[j]);
    float h2[64];
    #pragma unroll
    for (int j = 0; j < 64; ++j) h2[j] = b2[j];
    #pragma unroll
    for (int k = 0; k < 64; ++k) {
        const float hk = h1[k];
        #pragma unroll
        for (int j = 0; j < 64; ++j) h2[j] += hk * W2[k * 64 + j];
    }
    #pragma unroll
    for (int j = 0; j < 64; ++j) h2[j] = silu_f(h2[j]);
    float a0 = b3[0], a1 = b3[1], a2 = b3[2], a3 = b3[3];
    #pragma unroll
    for (int k = 0; k < 64; ++k) {
        const float hk = h2[k];
        a0 += hk * W3[k * 4 + 0];
        a1 += hk * W3[k * 4 + 1];
        a2 += hk * W3[k * 4 + 2];
        a3 += hk * W3[k * 4 + 3];
    }
    A[0] = a0; A[1] = a1; A[2] = a2; A[3] = a3;
}

template<int STRIDE>
__global__ __launch_bounds__(256) void qgnn_edge_kernel(
    const float* __restrict__ hr, const float* __restrict__ hi,
    const int* __restrict__ ei,
    const float* __restrict__ npar, const float* __restrict__ epar,
    const float* __restrict__ Wa, const float* __restrict__ ba,
    const float* __restrict__ Wr1, const float* __restrict__ br1,
    const float* __restrict__ Wr2, const float* __restrict__ br2,
    const float* __restrict__ Wr3, const float* __restrict__ br3,
    const float* __restrict__ Wi1, const float* __restrict__ bi1,
    const float* __restrict__ Wi2, const float* __restrict__ bi2,
    const float* __restrict__ Wi3, const float* __restrict__ bi3,
    float* __restrict__ aggout, int E)
{
    const int e = blockIdx.x * blockDim.x + threadIdx.x;
    if (e >= E) return;
    const int s = ei[e];
    const int r = ei[E + e];
    const float ep0 = epar[ei[2 * e + 0]];
    const float ep1 = epar[ei[2 * e + 1]];
    const float4 hrs = *reinterpret_cast<const float4*>(hr + 4 * (size_t)s);
    const float4 hrr = *reinterpret_cast<const float4*>(hr + 4 * (size_t)r);
    const float2 nps = *reinterpret_cast<const float2*>(npar + 2 * (size_t)s);
    const float2 npr = *reinterpret_cast<const float2*>(npar + 2 * (size_t)r);
    float x[14];
    x[0] = hrs.x; x[1] = hrs.y; x[2] = hrs.z; x[3] = hrs.w;
    x[4] = hrr.x; x[5] = hrr.y; x[6] = hrr.z; x[7] = hrr.w;
    x[8] = nps.x; x[9] = nps.y; x[10] = npr.x; x[11] = npr.y;
    x[12] = ep0;  x[13] = ep1;
    float Ar[4];
    mlp14_64_64_4(x, Wr1, br1, Wr2, br2, Wr3, br3, Ar);
    const float4 his = *reinterpret_cast<const float4*>(hi + 4 * (size_t)s);
    const float4 hir = *reinterpret_cast<const float4*>(hi + 4 * (size_t)r);
    x[0] = his.x; x[1] = his.y; x[2] = his.z; x[3] = his.w;
    x[4] = hir.x; x[5] = hir.y; x[6] = hir.z; x[7] = hir.w;
    float Ai[4];
    mlp14_64_64_4(x, Wi1, bi1, Wi2, bi2, Wi3, bi3, Ai);
    #pragma unroll
    for (int t = 0; t < 3; ++t) {
        float z = ba[t];
        #pragma unroll
        for (int j = 0; j < 4; ++j) z += Ai[j] * Wa[j * 3 + t];
        #pragma unroll
        for (int j = 0; j < 4; ++j) z += Ar[j] * Wa[(4 + j) * 3 + t];
        atomicAdd(aggout + (size_t)STRIDE * (size_t)r + t, tanh_f(z) * PI_F);
    }
}

// ---------------- node kernel ----------------
__device__ __forceinline__ float wrap_pi(float v) {
    float rm = fmodf(v + PI_F, TWO_PI_F);
    if (rm < 0.0f) rm += TWO_PI_F;
    return rm - PI_F;
}

template<int STRIDE, bool WRITE_COMPLEX>
__global__ __launch_bounds__(256) void qgnn_node_kernel(
    const float* __restrict__ hr,
    const float* __restrict__ hi,
    float* __restrict__ out, int N)
{
    const int n = blockIdx.x * blockDim.x + threadIdx.x;
    if (n >= N) return;
    const float a = wrap_pi(out[(size_t)STRIDE * n + 0]);
    const float b = wrap_pi(out[(size_t)STRIDE * n + 1]);
    const float c = wrap_pi(out[(size_t)STRIDE * n + 2]);
    const float cb = __cosf(0.5f * b);
    const float sb = __sinf(0.5f * b);
    const float hpc = 0.5f * (a + c);
    const float hmc = 0.5f * (a - c);
    const float cpc = __cosf(hpc), spc = __sinf(hpc);
    const float cmc = __cosf(hmc), smc = __sinf(hmc);
    float Ur[2][2], Ui[2][2];
    Ur[0][0] =  cpc * cb;  Ui[0][0] = -spc * cb;
    Ur[0][1] = -cmc * sb;  Ui[0][1] =  smc * sb;
    Ur[1][0] =  cmc * sb;  Ui[1][0] =  smc * sb;
    Ur[1][1] =  cpc * cb;  Ui[1][1] =  spc * cb;
    const float4 h4r = *reinterpret_cast<const float4*>(hr + 4 * (size_t)n);
    const float4 h4i = *reinterpret_cast<const float4*>(hi + 4 * (size_t)n);
    float Hr[2][2] = {{h4r.x, h4r.y}, {h4r.z, h4r.w}};
    float Hi[2][2] = {{h4i.x, h4i.y}, {h4i.z, h4i.w}};
    float Tr[2][2], Ti[2][2];
    #pragma unroll
    for (int p = 0; p < 2; ++p) {
        #pragma unroll
        for (int j = 0; j < 2; ++j) {
            float tr = 0.0f, ti = 0.0f;
            #pragma unroll
            for (int t = 0; t < 2; ++t) {
                tr += Hr[p][t] * Ur[j][t] + Hi[p][t] * Ui[j][t];
                ti += Hi[p][t] * Ur[j][t] - Hr[p][t] * Ui[j][t];
            }
            Tr[p][j] = tr; Ti[p][j] = ti;
        }
    }
    float orr[2][2], oii[2][2];
    #pragma unroll
    for (int i = 0; i < 2; ++i) {
        #pragma unroll
        for (int j = 0; j < 2; ++j) {
            float xr = 0.0f, xi = 0.0f;
            #pragma unroll
            for (int p = 0; p < 2; ++p) {
                xr += Ur[i][p] * Tr[p][j] - Ui[i][p] * Ti[p][j];
                xi += Ur[i][p] * Ti[p][j] + Ui[i][p] * Tr[p][j];
            }
            orr[i][j] = xr; oii[i][j] = xi;
        }
    }
    if (WRITE_COMPLEX) {
        float4* outv = reinterpret_cast<float4*>(out + (size_t)STRIDE * n);
        outv[0] = make_float4(orr[0][0], oii[0][0], orr[0][1], oii[0][1]);
        outv[1] = make_float4(orr[1][0], oii[1][0], orr[1][1], oii[1][1]);
    } else {
        *reinterpret_cast<float4*>(out + (size_t)STRIDE * n) =
            make_float4(orr[0][0], orr[0][1], orr[1][0], orr[1][1]);
    }
}

extern "C" void kernel_launch(void* const* d_in, const int* in_sizes, int n_in,
                              void* d_out, int out_size, void* d_ws, size_t ws_size,
                              hipStream_t stream) {
    const float* hr   = (const float*)d_in[0];
    const float* hi   = (const float*)d_in[1];
    const int*   ei   = (const int*)  d_in[2];
    const float* npar = (const float*)d_in[3];
    const float* epar = (const float*)d_in[4];
    const float* Wa  = (const float*)d_in[5];
    const float* ba  = (const float*)d_in[6];
    const float* Wr1 = (const float*)d_in[7];
    const float* br1 = (const float*)d_in[8];
    const float* Wr2 = (const float*)d_in[9];
    const float* br2 = (const float*)d_in[10];
    const float* Wr3 = (const float*)d_in[11];
    const float* br3 = (const float*)d_in[12];
    const float* Wi1 = (const float*)d_in[13];
    const float* bi1 = (const float*)d_in[14];
    const float* Wi2 = (const float*)d_in[15];
    const float* bi2 = (const float*)d_in[16];
    const float* Wi3 = (const float*)d_in[17];
    const float* bi3 = (const float*)d_in[18];

    const int N = in_sizes[0] / 4;   // h_i_real is (N,2,2)
    const int E = in_sizes[2] / 2;   // edge_index is (2,E)

    float* out = (float*)d_out;
    const bool cplx = (out_size >= 8 * N);
    const int stride = cplx ? 8 : 4;
    const int total = stride * N;
    qgnn_zero_kernel<<<(total + 255) / 256, 256, 0, stream>>>(out, total);

    const bool use_mfma = (ws_size >= (size_t)WS_BYTES_NEEDED);
    if (use_mfma) {
        qgnn_prep_kernel<<<56, 256, 0, stream>>>(Wr1, Wr2, Wr3, Wi1, Wi2, Wi3,
                                                 (unsigned short*)d_ws);
        qgnn_edge_mfma_kernel<<<(E + 63) / 64, 256, 0, stream>>>(
            hr, hi, ei, npar, epar, Wa, ba,
            br1, br2, br3, bi1, bi2, bi3,
            (const unsigned short*)d_ws, out, E, stride);
    } else if (cplx) {
        qgnn_edge_kernel<8><<<(E + 255) / 256, 256, 0, stream>>>(
            hr, hi, ei, npar, epar, Wa, ba,
            Wr1, br1, Wr2, br2, Wr3, br3,
            Wi1, bi1, Wi2, bi2, Wi3, bi3, out, E);
    } else {
        qgnn_edge_kernel<4><<<(E + 255) / 256, 256, 0, stream>>>(
            hr, hi, ei, npar, epar, Wa, ba,
            Wr1, br1, Wr2, br2, Wr3, br3,
            Wi1, bi1, Wi2, bi2, Wi3, bi3, out, E);
    }

    if (cplx) {
        qgnn_node_kernel<8, true><<<(N + 255) / 256, 256, 0, stream>>>(hr, hi, out, N);
    } else {
        qgnn_node_kernel<4, false><<<(N + 255) / 256, 256, 0, stream>>>(hr, hi, out, N);
    }
}

// Round 9
// 372.324 us; speedup vs baseline: 6.9504x; 1.4624x over previous
//
// Round 9: barrier-free MFMA pipeline. r8 was serialization-bound (10 barriers
// + 28.7KB weight re-stage per 64 edges; MfmaUtil 10%, VALUBusy 39%, no pipe
// saturated). Now: weights staged ONCE per block (57.3KB, one barrier), blocks
// grid-stride over tiles, each wave autonomously handles 16 edges with X
// gathered to registers and wave-private H buffers (no __syncthreads in loop).
#include <hip/hip_runtime.h>

#define PI_F     3.14159265358979323846f
#define TWO_PI_F 6.28318530717958647692f

typedef __attribute__((ext_vector_type(8))) short short8;
typedef __attribute__((ext_vector_type(4))) float f32x4;

__device__ __forceinline__ float fast_rcp(float x) { return __builtin_amdgcn_rcpf(x); }
__device__ __forceinline__ float silu_f(float v) { return v * fast_rcp(1.0f + __expf(-v)); }
__device__ __forceinline__ float tanh_f(float z) {
    float ez = __expf(2.0f * z);
    return 1.0f - 2.0f * fast_rcp(ez + 1.0f);
}

// bf16 round-to-nearest-even split helpers
__device__ __forceinline__ unsigned short f2bf(float f) {
    unsigned u = __float_as_uint(f);
    u += 0x7FFFu + ((u >> 16) & 1u);
    return (unsigned short)(u >> 16);
}
__device__ __forceinline__ float bf2f(unsigned short h) {
    return __uint_as_float(((unsigned)h) << 16);
}

// ---------------- prep: fragment-ordered bf16 hi/lo weight planes ----------
// Same layout as round 8 (validated): per MLP (u16): L1 [0,2048) KT=1 NT=4;
// L2 [2048,6144) KT=2 NT=4; L3 [6144,7168) KT=2 NT=1. MLP i at +7168.
// hi plane [0,14336), lo plane [14336,28672).
// Frag elem ((kt*NT+nt)*64+lane)*8+j = W[kt*32+8*(lane>>4)+j][nt*16+(lane&15)].
#define WS_U16_TOTAL 28672
#define WS_BYTES_NEEDED (WS_U16_TOTAL * 2)

__global__ __launch_bounds__(256) void qgnn_prep_kernel(
    const float* __restrict__ Wr1, const float* __restrict__ Wr2, const float* __restrict__ Wr3,
    const float* __restrict__ Wi1, const float* __restrict__ Wi2, const float* __restrict__ Wi3,
    unsigned short* __restrict__ wsu)
{
    int idx = blockIdx.x * 256 + threadIdx.x;
    if (idx >= 14336) return;
    int rel = idx;
    int half = (rel >= 7168);
    if (half) rel -= 7168;
    const float* W; int base, NT, Kr, Nr;
    if (rel < 2048)      { W = half ? Wi1 : Wr1; base = 0;    NT = 4; Kr = 14; Nr = 64; }
    else if (rel < 6144) { W = half ? Wi2 : Wr2; base = 2048; NT = 4; Kr = 64; Nr = 64; }
    else                 { W = half ? Wi3 : Wr3; base = 6144; NT = 1; Kr = 64; Nr = 4;  }
    int f = rel - base;
    int frag = f >> 9, rem = f & 511;
    int l = rem >> 3, j = rem & 7;
    int nt = frag % NT, kt = frag / NT;
    int k = kt * 32 + ((l >> 4) << 3) + j;
    int n = nt * 16 + (l & 15);
    float v = (k < Kr && n < Nr) ? W[k * Nr + n] : 0.0f;
    unsigned short hi = f2bf(v);
    unsigned short lo = f2bf(v - bf2f(hi));
    wsu[idx] = hi;
    wsu[14336 + idx] = lo;
}

__global__ __launch_bounds__(256) void qgnn_zero_kernel(float* __restrict__ p, int n) {
    const int i = blockIdx.x * blockDim.x + threadIdx.x;
    if (i < n) p[i] = 0.0f;
}

#define MFMA(a, b, c) __builtin_amdgcn_mfma_f32_16x16x32_bf16((a), (b), (c), 0, 0, 0)
#define NW 4   // waves per block

__global__ __launch_bounds__(256) void qgnn_edge_mfma_kernel(
    const float* __restrict__ hr, const float* __restrict__ hi_,
    const int* __restrict__ ei,
    const float* __restrict__ npar, const float* __restrict__ epar,
    const float* __restrict__ Wa, const float* __restrict__ ba,
    const float* __restrict__ br1, const float* __restrict__ br2, const float* __restrict__ br3,
    const float* __restrict__ bi1, const float* __restrict__ bi2, const float* __restrict__ bi3,
    const unsigned short* __restrict__ wsu,
    float* __restrict__ aggout, int E, int stride)
{
    __shared__ __align__(16) unsigned short sW[WS_U16_TOTAL];      // 57344 B
    __shared__ __align__(16) unsigned short sHh[NW][16 * 72];      // 4x2304 B
    __shared__ __align__(16) unsigned short sHl[NW][16 * 72];      // 4x2304 B
    __shared__ __align__(16) float sH3[NW][16 * 8];                // 4x512 B

    // ---- stage ALL weights once (the only barrier in this kernel) ----
    for (int o = threadIdx.x * 8; o < WS_U16_TOTAL; o += 256 * 8)
        *reinterpret_cast<uint4*>(sW + o) = *reinterpret_cast<const uint4*>(wsu + o);
    __syncthreads();

    const int tid = threadIdx.x, w = tid >> 6, lane = tid & 63;
    const int m16 = lane & 15, g = lane >> 4;
    unsigned short* Hh = sHh[w];
    unsigned short* Hl = sHl[w];
    float* H3 = sH3[w];

    // ---- per-lane constants preloaded once ----
    float br1v[4], br2v[4], bi1v[4], bi2v[4];
    #pragma unroll
    for (int q = 0; q < 4; ++q) {
        br1v[q] = br1[q * 16 + m16];
        br2v[q] = br2[q * 16 + m16];
        bi1v[q] = bi1[q * 16 + m16];
        bi2v[q] = bi2[q * 16 + m16];
    }
    const float br3v = (m16 < 4) ? br3[m16] : 0.0f;
    const float bi3v = (m16 < 4) ? bi3[m16] : 0.0f;
    float wav[24], bav[3];
    #pragma unroll
    for (int q = 0; q < 24; ++q) wav[q] = Wa[q];
    #pragma unroll
    for (int q = 0; q < 3; ++q) bav[q] = ba[q];

    const int ntiles = (E + 15) >> 4;
    for (int tile = blockIdx.x * NW + w; tile < ntiles; tile += gridDim.x * NW) {
        const int em = tile * 16 + m16;
        const bool valid = (em < E);

        // ---- gather X straight into registers (no LDS, no barrier) ----
        float f0[8], f1[8];
        #pragma unroll
        for (int j = 0; j < 8; ++j) { f0[j] = 0.0f; f1[j] = 0.0f; }
        if (valid && g < 2) {
            const int s = ei[em], r = ei[E + em];
            if (g == 0) {
                const float4 a = *reinterpret_cast<const float4*>(hr  + 4 * (size_t)s);
                const float4 b = *reinterpret_cast<const float4*>(hr  + 4 * (size_t)r);
                const float4 c = *reinterpret_cast<const float4*>(hi_ + 4 * (size_t)s);
                const float4 d = *reinterpret_cast<const float4*>(hi_ + 4 * (size_t)r);
                f0[0] = a.x; f0[1] = a.y; f0[2] = a.z; f0[3] = a.w;
                f0[4] = b.x; f0[5] = b.y; f0[6] = b.z; f0[7] = b.w;
                f1[0] = c.x; f1[1] = c.y; f1[2] = c.z; f1[3] = c.w;
                f1[4] = d.x; f1[5] = d.y; f1[6] = d.z; f1[7] = d.w;
            } else {
                const float2 n0 = *reinterpret_cast<const float2*>(npar + 2 * (size_t)s);
                const float2 n1 = *reinterpret_cast<const float2*>(npar + 2 * (size_t)r);
                const float e0 = epar[ei[2 * em + 0]];
                const float e1 = epar[ei[2 * em + 1]];
                f0[0] = n0.x; f0[1] = n0.y; f0[2] = n1.x; f0[3] = n1.y;
                f0[4] = e0;   f0[5] = e1;
                #pragma unroll
                for (int j = 0; j < 6; ++j) f1[j] = f0[j];
            }
        }
        short8 xh0, xl0, xh1, xl1;
        #pragma unroll
        for (int j = 0; j < 8; ++j) {
            unsigned short h0 = f2bf(f0[j]);
            xh0[j] = (short)h0; xl0[j] = (short)f2bf(f0[j] - bf2f(h0));
            unsigned short h1 = f2bf(f1[j]);
            xh1[j] = (short)h1; xl1[j] = (short)f2bf(f1[j] - bf2f(h1));
        }

        #pragma unroll 1
        for (int mlp = 0; mlp < 2; ++mlp) {
            const unsigned short* wh = sW + mlp * 7168;
            const unsigned short* wl = sW + 14336 + mlp * 7168;
            const short8 ah = mlp ? xh1 : xh0;
            const short8 al = mlp ? xl1 : xl0;

            // ---------- Layer 1: (16x32) @ (32x64) ----------
            #pragma unroll
            for (int nt = 0; nt < 4; ++nt) {
                const float bv = mlp ? bi1v[nt] : br1v[nt];
                f32x4 acc = {bv, bv, bv, bv};
                const short8 bh = *reinterpret_cast<const short8*>(&wh[(nt * 64 + lane) * 8]);
                const short8 bl = *reinterpret_cast<const short8*>(&wl[(nt * 64 + lane) * 8]);
                acc = MFMA(al, bh, acc);
                acc = MFMA(ah, bl, acc);
                acc = MFMA(ah, bh, acc);
                #pragma unroll
                for (int i = 0; i < 4; ++i) {
                    const float hv = silu_f(acc[i]);
                    const int row = 4 * g + i, col = nt * 16 + m16;
                    const unsigned short hh = f2bf(hv);
                    Hh[row * 72 + col] = hh;
                    Hl[row * 72 + col] = f2bf(hv - bf2f(hh));
                }
            }

            // ---------- Layer 2: (16x64) @ (64x64) ----------
            {
                const short8 a0h = *reinterpret_cast<const short8*>(&Hh[m16 * 72 + 8 * g]);
                const short8 a0l = *reinterpret_cast<const short8*>(&Hl[m16 * 72 + 8 * g]);
                const short8 a1h = *reinterpret_cast<const short8*>(&Hh[m16 * 72 + 32 + 8 * g]);
                const short8 a1l = *reinterpret_cast<const short8*>(&Hl[m16 * 72 + 32 + 8 * g]);
                #pragma unroll
                for (int nt = 0; nt < 4; ++nt) {
                    const float bv = mlp ? bi2v[nt] : br2v[nt];
                    f32x4 acc = {bv, bv, bv, bv};
                    const short8 bh0 = *reinterpret_cast<const short8*>(&wh[2048 + ((0 * 4 + nt) * 64 + lane) * 8]);
                    const short8 bl0 = *reinterpret_cast<const short8*>(&wl[2048 + ((0 * 4 + nt) * 64 + lane) * 8]);
                    const short8 bh1 = *reinterpret_cast<const short8*>(&wh[2048 + ((1 * 4 + nt) * 64 + lane) * 8]);
                    const short8 bl1 = *reinterpret_cast<const short8*>(&wl[2048 + ((1 * 4 + nt) * 64 + lane) * 8]);
                    acc = MFMA(a0l, bh0, acc);
                    acc = MFMA(a0h, bl0, acc);
                    acc = MFMA(a0h, bh0, acc);
                    acc = MFMA(a1l, bh1, acc);
                    acc = MFMA(a1h, bl1, acc);
                    acc = MFMA(a1h, bh1, acc);
                    #pragma unroll
                    for (int i = 0; i < 4; ++i) {
                        const float hv = silu_f(acc[i]);
                        const int row = 4 * g + i, col = nt * 16 + m16;
                        const unsigned short hh = f2bf(hv);
                        Hh[row * 72 + col] = hh;     // overwrite ok: a-frags already in regs
                        Hl[row * 72 + col] = f2bf(hv - bf2f(hh));
                    }
                }
            }

            // ---------- Layer 3: (16x64) @ (64x16), 4 valid cols ----------
            {
                const short8 a0h = *reinterpret_cast<const short8*>(&Hh[m16 * 72 + 8 * g]);
                const short8 a0l = *reinterpret_cast<const short8*>(&Hl[m16 * 72 + 8 * g]);
                const short8 a1h = *reinterpret_cast<const short8*>(&Hh[m16 * 72 + 32 + 8 * g]);
                const short8 a1l = *reinterpret_cast<const short8*>(&Hl[m16 * 72 + 32 + 8 * g]);
                const float bv = mlp ? bi3v : br3v;
                f32x4 acc = {bv, bv, bv, bv};
                const short8 bh0 = *reinterpret_cast<const short8*>(&wh[6144 + (0 * 64 + lane) * 8]);
                const short8 bl0 = *reinterpret_cast<const short8*>(&wl[6144 + (0 * 64 + lane) * 8]);
                const short8 bh1 = *reinterpret_cast<const short8*>(&wh[6144 + (1 * 64 + lane) * 8]);
                const short8 bl1 = *reinterpret_cast<const short8*>(&wl[6144 + (1 * 64 + lane) * 8]);
                acc = MFMA(a0l, bh0, acc);
                acc = MFMA(a0h, bl0, acc);
                acc = MFMA(a0h, bh0, acc);
                acc = MFMA(a1l, bh1, acc);
                acc = MFMA(a1h, bl1, acc);
                acc = MFMA(a1h, bh1, acc);
                if (m16 < 4) {
                    #pragma unroll
                    for (int i = 0; i < 4; ++i)
                        H3[(4 * g + i) * 8 + m16 + 4 * mlp] = acc[i];
                }
            }
        }

        // ---- epilogue: 16 lanes, one edge each (wave-internal LDS, no barrier)
        if (lane < 16) {
            const int e2 = tile * 16 + lane;
            if (e2 < E) {
                const float4 Ai4 = *reinterpret_cast<const float4*>(&H3[lane * 8 + 4]);
                const float4 Ar4 = *reinterpret_cast<const float4*>(&H3[lane * 8 + 0]);
                const float Ai[4] = {Ai4.x, Ai4.y, Ai4.z, Ai4.w};
                const float Ar[4] = {Ar4.x, Ar4.y, Ar4.z, Ar4.w};
                const int r = ei[E + e2];
                #pragma unroll
                for (int t = 0; t < 3; ++t) {
                    float z = bav[t];
                    #pragma unroll
                    for (int j = 0; j < 4; ++j) z += Ai[j] * wav[j * 3 + t];
                    #pragma unroll
                    for (int j = 0; j < 4; ++j) z += Ar[j] * wav[(4 + j) * 3 + t];
                    atomicAdd(aggout + (size_t)stride * (size_t)r + t, tanh_f(z) * PI_F);
                }
            }
        }
    }
}

// ---------------- round-6 scalar fallback (ws too small) ----------------
__device__ __forceinline__ void mlp14_64_64_4(
    const float x[14],
    const float* __restrict__ W1, const float* __restrict__ b1,
    const float* __restrict__ W2, const float* __restrict__ b2,
    const float* __restrict__ W3, const float* __restrict__ b3,
    float A[4])
{
    float h1[64];
    #pragma unroll
    for (int j = 0; j < 64; ++j) h1[j] = b1[j];
    #pragma unroll
    for (int k = 0; k < 14; ++k) {
        const float xk = x[k];
        #pragma unroll
        for (int j = 0; j < 64; ++j) h1[j] += xk * W1[k * 64 + j];
    }
    #pragma unroll
    for (int j = 0; j < 64; ++j) h1[j] = silu_f(h1[j]);
    float h2[64];
    #pragma unroll
    for (int j = 0; j < 64; ++j) h2[j] = b2[j];
    #pragma unroll
    for (int k = 0; k < 64; ++k) {
        const float hk = h1[k];
        #pragma unroll
        for (int j = 0; j < 64; ++j) h2[j] += hk * W2[k * 64 + j];
    }
    #pragma unroll
    for (int j = 0; j < 64; ++j) h2[j] = silu_f(h2[j]);
    float a0 = b3[0], a1 = b3[1], a2 = b3[2], a3 = b3[3];
    #pragma unroll
    for (int k = 0; k < 64; ++k) {
        const float hk = h2[k];
        a0 += hk * W3[k * 4 + 0];
        a1 += hk * W3[k * 4 + 1];
        a2 += hk * W3[k * 4 + 2];
        a3 += hk * W3[k * 4 + 3];
    }
    A[0] = a0; A[1] = a1; A[2] = a2; A[3] = a3;
}

template<int STRIDE>
__global__ __launch_bounds__(256) void qgnn_edge_kernel(
    const float* __restrict__ hr, const float* __restrict__ hi,
    const int* __restrict__ ei,
    const float* __restrict__ npar, const float* __restrict__ epar,
    const float* __restrict__ Wa, const float* __restrict__ ba,
    const float* __restrict__ Wr1, const float* __restrict__ br1,
    const float* __restrict__ Wr2, const float* __restrict__ br2,
    const float* __restrict__ Wr3, const float* __restrict__ br3,
    const float* __restrict__ Wi1, const float* __restrict__ bi1,
    const float* __restrict__ Wi2, const float* __restrict__ bi2,
    const float* __restrict__ Wi3, const float* __restrict__ bi3,
    float* __restrict__ aggout, int E)
{
    const int e = blockIdx.x * blockDim.x + threadIdx.x;
    if (e >= E) return;
    const int s = ei[e];
    const int r = ei[E + e];
    const float ep0 = epar[ei[2 * e + 0]];
    const float ep1 = epar[ei[2 * e + 1]];
    const float4 hrs = *reinterpret_cast<const float4*>(hr + 4 * (size_t)s);
    const float4 hrr = *reinterpret_cast<const float4*>(hr + 4 * (size_t)r);
    const float2 nps = *reinterpret_cast<const float2*>(npar + 2 * (size_t)s);
    const float2 npr = *reinterpret_cast<const float2*>(npar + 2 * (size_t)r);
    float x[14];
    x[0] = hrs.x; x[1] = hrs.y; x[2] = hrs.z; x[3] = hrs.w;
    x[4] = hrr.x; x[5] = hrr.y; x[6] = hrr.z; x[7] = hrr.w;
    x[8] = nps.x; x[9] = nps.y; x[10] = npr.x; x[11] = npr.y;
    x[12] = ep0;  x[13] = ep1;
    float Ar[4];
    mlp14_64_64_4(x, Wr1, br1, Wr2, br2, Wr3, br3, Ar);
    const float4 his = *reinterpret_cast<const float4*>(hi + 4 * (size_t)s);
    const float4 hir = *reinterpret_cast<const float4*>(hi + 4 * (size_t)r);
    x[0] = his.x; x[1] = his.y; x[2] = his.z; x[3] = his.w;
    x[4] = hir.x; x[5] = hir.y; x[6] = hir.z; x[7] = hir.w;
    float Ai[4];
    mlp14_64_64_4(x, Wi1, bi1, Wi2, bi2, Wi3, bi3, Ai);
    #pragma unroll
    for (int t = 0; t < 3; ++t) {
        float z = ba[t];
        #pragma unroll
        for (int j = 0; j < 4; ++j) z += Ai[j] * Wa[j * 3 + t];
        #pragma unroll
        for (int j = 0; j < 4; ++j) z += Ar[j] * Wa[(4 + j) * 3 + t];
        atomicAdd(aggout + (size_t)STRIDE * (size_t)r + t, tanh_f(z) * PI_F);
    }
}

// ---------------- node kernel ----------------
__device__ __forceinline__ float wrap_pi(float v) {
    float rm = fmodf(v + PI_F, TWO_PI_F);
    if (rm < 0.0f) rm += TWO_PI_F;
    return rm - PI_F;
}

template<int STRIDE, bool WRITE_COMPLEX>
__global__ __launch_bounds__(256) void qgnn_node_kernel(
    const float* __restrict__ hr,
    const float* __restrict__ hi,
    float* __restrict__ out, int N)
{
    const int n = blockIdx.x * blockDim.x + threadIdx.x;
    if (n >= N) return;
    const float a = wrap_pi(out[(size_t)STRIDE * n + 0]);
    const float b = wrap_pi(out[(size_t)STRIDE * n + 1]);
    const float c = wrap_pi(out[(size_t)STRIDE * n + 2]);
    const float cb = __cosf(0.5f * b);
    const float sb = __sinf(0.5f * b);
    const float hpc = 0.5f * (a + c);
    const float hmc = 0.5f * (a - c);
    const float cpc = __cosf(hpc), spc = __sinf(hpc);
    const float cmc = __cosf(hmc), smc = __sinf(hmc);
    float Ur[2][2], Ui[2][2];
    Ur[0][0] =  cpc * cb;  Ui[0][0] = -spc * cb;
    Ur[0][1] = -cmc * sb;  Ui[0][1] =  smc * sb;
    Ur[1][0] =  cmc * sb;  Ui[1][0] =  smc * sb;
    Ur[1][1] =  cpc * cb;  Ui[1][1] =  spc * cb;
    const float4 h4r = *reinterpret_cast<const float4*>(hr + 4 * (size_t)n);
    const float4 h4i = *reinterpret_cast<const float4*>(hi + 4 * (size_t)n);
    float Hr[2][2] = {{h4r.x, h4r.y}, {h4r.z, h4r.w}};
    float Hi[2][2] = {{h4i.x, h4i.y}, {h4i.z, h4i.w}};
    float Tr[2][2], Ti[2][2];
    #pragma unroll
    for (int p = 0; p < 2; ++p) {
        #pragma unroll
        for (int j = 0; j < 2; ++j) {
            float tr = 0.0f, ti = 0.0f;
            #pragma unroll
            for (int t = 0; t < 2; ++t) {
                tr += Hr[p][t] * Ur[j][t] + Hi[p][t] * Ui[j][t];
                ti += Hi[p][t] * Ur[j][t] - Hr[p][t] * Ui[j][t];
            }
            Tr[p][j] = tr; Ti[p][j] = ti;
        }
    }
    float orr[2][2], oii[2][2];
    #pragma unroll
    for (int i = 0; i < 2; ++i) {
        #pragma unroll
        for (int j = 0; j < 2; ++j) {
            float xr = 0.0f, xi = 0.0f;
            #pragma unroll
            for (int p = 0; p < 2; ++p) {
                xr += Ur[i][p] * Tr[p][j] - Ui[i][p] * Ti[p][j];
                xi += Ur[i][p] * Ti[p][j] + Ui[i][p] * Tr[p][j];
            }
            orr[i][j] = xr; oii[i][j] = xi;
        }
    }
    if (WRITE_COMPLEX) {
        float4* outv = reinterpret_cast<float4*>(out + (size_t)STRIDE * n);
        outv[0] = make_float4(orr[0][0], oii[0][0], orr[0][1], oii[0][1]);
        outv[1] = make_float4(orr[1][0], oii[1][0], orr[1][1], oii[1][1]);
    } else {
        *reinterpret_cast<float4*>(out + (size_t)STRIDE * n) =
            make_float4(orr[0][0], orr[0][1], orr[1][0], orr[1][1]);
    }
}

extern "C" void kernel_launch(void* const* d_in, const int* in_sizes, int n_in,
                              void* d_out, int out_size, void* d_ws, size_t ws_size,
                              hipStream_t stream) {
    const float* hr   = (const float*)d_in[0];
    const float* hi   = (const float*)d_in[1];
    const int*   ei   = (const int*)  d_in[2];
    const float* npar = (const float*)d_in[3];
    const float* epar = (const float*)d_in[4];
    const float* Wa  = (const float*)d_in[5];
    const float* ba  = (const float*)d_in[6];
    const float* Wr1 = (const float*)d_in[7];
    const float* br1 = (const float*)d_in[8];
    const float* Wr2 = (const float*)d_in[9];
    const float* br2 = (const float*)d_in[10];
    const float* Wr3 = (const float*)d_in[11];
    const float* br3 = (const float*)d_in[12];
    const float* Wi1 = (const float*)d_in[13];
    const float* bi1 = (const float*)d_in[14];
    const float* Wi2 = (const float*)d_in[15];
    const float* bi2 = (const float*)d_in[16];
    const float* Wi3 = (const float*)d_in[17];
    const float* bi3 = (const float*)d_in[18];

    const int N = in_sizes[0] / 4;   // h_i_real is (N,2,2)
    const int E = in_sizes[2] / 2;   // edge_index is (2,E)

    float* out = (float*)d_out;
    const bool cplx = (out_size >= 8 * N);
    const int stride = cplx ? 8 : 4;
    const int total = stride * N;
    qgnn_zero_kernel<<<(total + 255) / 256, 256, 0, stream>>>(out, total);

    const bool use_mfma = (ws_size >= (size_t)WS_BYTES_NEEDED);
    if (use_mfma) {
        qgnn_prep_kernel<<<56, 256, 0, stream>>>(Wr1, Wr2, Wr3, Wi1, Wi2, Wi3,
                                                 (unsigned short*)d_ws);
        const int ntiles = (E + 15) / 16;
        int blocks = (ntiles + NW - 1) / NW;
        if (blocks > 2048) blocks = 2048;
        qgnn_edge_mfma_kernel<<<blocks, 256, 0, stream>>>(
            hr, hi, ei, npar, epar, Wa, ba,
            br1, br2, br3, bi1, bi2, bi3,
            (const unsigned short*)d_ws, out, E, stride);
    } else if (cplx) {
        qgnn_edge_kernel<8><<<(E + 255) / 256, 256, 0, stream>>>(
            hr, hi, ei, npar, epar, Wa, ba,
            Wr1, br1, Wr2, br2, Wr3, br3,
            Wi1, bi1, Wi2, bi2, Wi3, bi3, out, E);
    } else {
        qgnn_edge_kernel<4><<<(E + 255) / 256, 256, 0, stream>>>(
            hr, hi, ei, npar, epar, Wa, ba,
            Wr1, br1, Wr2, br2, Wr3, br3,
            Wi1, bi1, Wi2, bi2, Wi3, bi3, out, E);
    }

    if (cplx) {
        qgnn_node_kernel<8, true><<<(N + 255) / 256, 256, 0, stream>>>(hr, hi, out, N);
    } else {
        qgnn_node_kernel<4, false><<<(N + 255) / 256, 256, 0, stream>>>(hr, hi, out, N);
    }
}

// Round 10
// 347.051 us; speedup vs baseline: 7.4566x; 1.0728x over previous
//
// Round 10: cheapen the hi/lo split (truncation split: AND+SUB+2xSHR = 5 VALU
// per element, replacing double-RNE f2bf ~10-16 VALU). r9 counters: VALU-bound
// (VALUBusy 60%, MfmaUtil 15%, occ 22%); split machinery was the VALU majority.
// Structure identical to r9 (barrier-free, weights staged once, 16 edges/wave).
#include <hip/hip_runtime.h>

#define PI_F     3.14159265358979323846f
#define TWO_PI_F 6.28318530717958647692f

typedef __attribute__((ext_vector_type(8))) short short8;
typedef __attribute__((ext_vector_type(4))) float f32x4;

__device__ __forceinline__ float fast_rcp(float x) { return __builtin_amdgcn_rcpf(x); }
__device__ __forceinline__ float silu_f(float v) { return v * fast_rcp(1.0f + __expf(-v)); }
__device__ __forceinline__ float tanh_f(float z) {
    float ez = __expf(2.0f * z);
    return 1.0f - 2.0f * fast_rcp(ez + 1.0f);
}

// RNE bf16 helpers (prep kernel only — runs once, accuracy-first)
__device__ __forceinline__ unsigned short f2bf(float f) {
    unsigned u = __float_as_uint(f);
    u += 0x7FFFu + ((u >> 16) & 1u);
    return (unsigned short)(u >> 16);
}
__device__ __forceinline__ float bf2f(unsigned short h) {
    return __uint_as_float(((unsigned)h) << 16);
}

// Truncation split (hot path): hi = trunc16(v) exact-in-bf16, lo = trunc16(v-hi).
// v = hi + lo + err, |err| <= 2^-16 |v|. 5 VALU/elem.
__device__ __forceinline__ void split_trunc(float v, unsigned short& h, unsigned short& l) {
    const unsigned u = __float_as_uint(v);
    const float hf = __uint_as_float(u & 0xFFFF0000u);
    h = (unsigned short)(u >> 16);
    l = (unsigned short)(__float_as_uint(v - hf) >> 16);
}

// ---------------- prep: fragment-ordered bf16 hi/lo weight planes ----------
// Layout (validated r8/r9): per MLP (u16): L1 [0,2048) KT=1 NT=4; L2
// [2048,6144) KT=2 NT=4; L3 [6144,7168) KT=2 NT=1. MLP i at +7168.
// hi plane [0,14336), lo plane [14336,28672).
// Frag elem ((kt*NT+nt)*64+lane)*8+j = W[kt*32+8*(lane>>4)+j][nt*16+(lane&15)].
#define WS_U16_TOTAL 28672
#define WS_BYTES_NEEDED (WS_U16_TOTAL * 2)

__global__ __launch_bounds__(256) void qgnn_prep_kernel(
    const float* __restrict__ Wr1, const float* __restrict__ Wr2, const float* __restrict__ Wr3,
    const float* __restrict__ Wi1, const float* __restrict__ Wi2, const float* __restrict__ Wi3,
    unsigned short* __restrict__ wsu)
{
    int idx = blockIdx.x * 256 + threadIdx.x;
    if (idx >= 14336) return;
    int rel = idx;
    int half = (rel >= 7168);
    if (half) rel -= 7168;
    const float* W; int base, NT, Kr, Nr;
    if (rel < 2048)      { W = half ? Wi1 : Wr1; base = 0;    NT = 4; Kr = 14; Nr = 64; }
    else if (rel < 6144) { W = half ? Wi2 : Wr2; base = 2048; NT = 4; Kr = 64; Nr = 64; }
    else                 { W = half ? Wi3 : Wr3; base = 6144; NT = 1; Kr = 64; Nr = 4;  }
    int f = rel - base;
    int frag = f >> 9, rem = f & 511;
    int l = rem >> 3, j = rem & 7;
    int nt = frag % NT, kt = frag / NT;
    int k = kt * 32 + ((l >> 4) << 3) + j;
    int n = nt * 16 + (l & 15);
    float v = (k < Kr && n < Nr) ? W[k * Nr + n] : 0.0f;
    unsigned short hi = f2bf(v);
    unsigned short lo = f2bf(v - bf2f(hi));
    wsu[idx] = hi;
    wsu[14336 + idx] = lo;
}

__global__ __launch_bounds__(256) void qgnn_zero_kernel(float* __restrict__ p, int n) {
    const int i = blockIdx.x * blockDim.x + threadIdx.x;
    if (i < n) p[i] = 0.0f;
}

#define MFMA(a, b, c) __builtin_amdgcn_mfma_f32_16x16x32_bf16((a), (b), (c), 0, 0, 0)
#define NW 4   // waves per block

__global__ __launch_bounds__(256) void qgnn_edge_mfma_kernel(
    const float* __restrict__ hr, const float* __restrict__ hi_,
    const int* __restrict__ ei,
    const float* __restrict__ npar, const float* __restrict__ epar,
    const float* __restrict__ Wa, const float* __restrict__ ba,
    const float* __restrict__ br1, const float* __restrict__ br2, const float* __restrict__ br3,
    const float* __restrict__ bi1, const float* __restrict__ bi2, const float* __restrict__ bi3,
    const unsigned short* __restrict__ wsu,
    float* __restrict__ aggout, int E, int stride)
{
    __shared__ __align__(16) unsigned short sW[WS_U16_TOTAL];      // 57344 B
    __shared__ __align__(16) unsigned short sHh[NW][16 * 72];      // 4x2304 B
    __shared__ __align__(16) unsigned short sHl[NW][16 * 72];      // 4x2304 B
    __shared__ __align__(16) float sH3[NW][16 * 8];                // 4x512 B

    // ---- stage ALL weights once (the only barrier in this kernel) ----
    for (int o = threadIdx.x * 8; o < WS_U16_TOTAL; o += 256 * 8)
        *reinterpret_cast<uint4*>(sW + o) = *reinterpret_cast<const uint4*>(wsu + o);
    __syncthreads();

    const int tid = threadIdx.x, w = tid >> 6, lane = tid & 63;
    const int m16 = lane & 15, g = lane >> 4;
    unsigned short* Hh = sHh[w];
    unsigned short* Hl = sHl[w];
    float* H3 = sH3[w];

    // ---- per-lane constants preloaded once ----
    float br1v[4], br2v[4], bi1v[4], bi2v[4];
    #pragma unroll
    for (int q = 0; q < 4; ++q) {
        br1v[q] = br1[q * 16 + m16];
        br2v[q] = br2[q * 16 + m16];
        bi1v[q] = bi1[q * 16 + m16];
        bi2v[q] = bi2[q * 16 + m16];
    }
    const float br3v = (m16 < 4) ? br3[m16] : 0.0f;
    const float bi3v = (m16 < 4) ? bi3[m16] : 0.0f;
    float wav[24], bav[3];
    #pragma unroll
    for (int q = 0; q < 24; ++q) wav[q] = Wa[q];
    #pragma unroll
    for (int q = 0; q < 3; ++q) bav[q] = ba[q];

    const int ntiles = (E + 15) >> 4;
    for (int tile = blockIdx.x * NW + w; tile < ntiles; tile += gridDim.x * NW) {
        const int em = tile * 16 + m16;
        const bool valid = (em < E);

        // ---- gather X straight into registers (no LDS, no barrier) ----
        float f0[8], f1[8];
        #pragma unroll
        for (int j = 0; j < 8; ++j) { f0[j] = 0.0f; f1[j] = 0.0f; }
        if (valid && g < 2) {
            const int s = ei[em], r = ei[E + em];
            if (g == 0) {
                const float4 a = *reinterpret_cast<const float4*>(hr  + 4 * (size_t)s);
                const float4 b = *reinterpret_cast<const float4*>(hr  + 4 * (size_t)r);
                const float4 c = *reinterpret_cast<const float4*>(hi_ + 4 * (size_t)s);
                const float4 d = *reinterpret_cast<const float4*>(hi_ + 4 * (size_t)r);
                f0[0] = a.x; f0[1] = a.y; f0[2] = a.z; f0[3] = a.w;
                f0[4] = b.x; f0[5] = b.y; f0[6] = b.z; f0[7] = b.w;
                f1[0] = c.x; f1[1] = c.y; f1[2] = c.z; f1[3] = c.w;
                f1[4] = d.x; f1[5] = d.y; f1[6] = d.z; f1[7] = d.w;
            } else {
                const float2 n0 = *reinterpret_cast<const float2*>(npar + 2 * (size_t)s);
                const float2 n1 = *reinterpret_cast<const float2*>(npar + 2 * (size_t)r);
                const float e0 = epar[ei[2 * em + 0]];
                const float e1 = epar[ei[2 * em + 1]];
                f0[0] = n0.x; f0[1] = n0.y; f0[2] = n1.x; f0[3] = n1.y;
                f0[4] = e0;   f0[5] = e1;
                #pragma unroll
                for (int j = 0; j < 6; ++j) f1[j] = f0[j];
            }
        }
        short8 xh0, xl0, xh1, xl1;
        #pragma unroll
        for (int j = 0; j < 8; ++j) {
            unsigned short h, l;
            split_trunc(f0[j], h, l);
            xh0[j] = (short)h; xl0[j] = (short)l;
            split_trunc(f1[j], h, l);
            xh1[j] = (short)h; xl1[j] = (short)l;
        }

        #pragma unroll 1
        for (int mlp = 0; mlp < 2; ++mlp) {
            const unsigned short* wh = sW + mlp * 7168;
            const unsigned short* wl = sW + 14336 + mlp * 7168;
            const short8 ah = mlp ? xh1 : xh0;
            const short8 al = mlp ? xl1 : xl0;

            // ---------- Layer 1: (16x32) @ (32x64) ----------
            #pragma unroll
            for (int nt = 0; nt < 4; ++nt) {
                const float bv = mlp ? bi1v[nt] : br1v[nt];
                f32x4 acc = {bv, bv, bv, bv};
                const short8 bh = *reinterpret_cast<const short8*>(&wh[(nt * 64 + lane) * 8]);
                const short8 bl = *reinterpret_cast<const short8*>(&wl[(nt * 64 + lane) * 8]);
                acc = MFMA(al, bh, acc);
                acc = MFMA(ah, bl, acc);
                acc = MFMA(ah, bh, acc);
                #pragma unroll
                for (int i = 0; i < 4; ++i) {
                    const float hv = silu_f(acc[i]);
                    const int row = 4 * g + i, col = nt * 16 + m16;
                    unsigned short hh, hl;
                    split_trunc(hv, hh, hl);
                    Hh[row * 72 + col] = hh;
                    Hl[row * 72 + col] = hl;
                }
            }

            // ---------- Layer 2: (16x64) @ (64x64) ----------
            {
                const short8 a0h = *reinterpret_cast<const short8*>(&Hh[m16 * 72 + 8 * g]);
                const short8 a0l = *reinterpret_cast<const short8*>(&Hl[m16 * 72 + 8 * g]);
                const short8 a1h = *reinterpret_cast<const short8*>(&Hh[m16 * 72 + 32 + 8 * g]);
                const short8 a1l = *reinterpret_cast<const short8*>(&Hl[m16 * 72 + 32 + 8 * g]);
                #pragma unroll
                for (int nt = 0; nt < 4; ++nt) {
                    const float bv = mlp ? bi2v[nt] : br2v[nt];
                    f32x4 acc = {bv, bv, bv, bv};
                    const short8 bh0 = *reinterpret_cast<const short8*>(&wh[2048 + ((0 * 4 + nt) * 64 + lane) * 8]);
                    const short8 bl0 = *reinterpret_cast<const short8*>(&wl[2048 + ((0 * 4 + nt) * 64 + lane) * 8]);
                    const short8 bh1 = *reinterpret_cast<const short8*>(&wh[2048 + ((1 * 4 + nt) * 64 + lane) * 8]);
                    const short8 bl1 = *reinterpret_cast<const short8*>(&wl[2048 + ((1 * 4 + nt) * 64 + lane) * 8]);
                    acc = MFMA(a0l, bh0, acc);
                    acc = MFMA(a0h, bl0, acc);
                    acc = MFMA(a0h, bh0, acc);
                    acc = MFMA(a1l, bh1, acc);
                    acc = MFMA(a1h, bl1, acc);
                    acc = MFMA(a1h, bh1, acc);
                    #pragma unroll
                    for (int i = 0; i < 4; ++i) {
                        const float hv = silu_f(acc[i]);
                        const int row = 4 * g + i, col = nt * 16 + m16;
                        unsigned short hh, hl;
                        split_trunc(hv, hh, hl);
                        Hh[row * 72 + col] = hh;     // overwrite ok: a-frags already in regs
                        Hl[row * 72 + col] = hl;
                    }
                }
            }

            // ---------- Layer 3: (16x64) @ (64x16), 4 valid cols ----------
            {
                const short8 a0h = *reinterpret_cast<const short8*>(&Hh[m16 * 72 + 8 * g]);
                const short8 a0l = *reinterpret_cast<const short8*>(&Hl[m16 * 72 + 8 * g]);
                const short8 a1h = *reinterpret_cast<const short8*>(&Hh[m16 * 72 + 32 + 8 * g]);
                const short8 a1l = *reinterpret_cast<const short8*>(&Hl[m16 * 72 + 32 + 8 * g]);
                const float bv = mlp ? bi3v : br3v;
                f32x4 acc = {bv, bv, bv, bv};
                const short8 bh0 = *reinterpret_cast<const short8*>(&wh[6144 + (0 * 64 + lane) * 8]);
                const short8 bl0 = *reinterpret_cast<const short8*>(&wl[6144 + (0 * 64 + lane) * 8]);
                const short8 bh1 = *reinterpret_cast<const short8*>(&wh[6144 + (1 * 64 + lane) * 8]);
                const short8 bl1 = *reinterpret_cast<const short8*>(&wl[6144 + (1 * 64 + lane) * 8]);
                acc = MFMA(a0l, bh0, acc);
                acc = MFMA(a0h, bl0, acc);
                acc = MFMA(a0h, bh0, acc);
                acc = MFMA(a1l, bh1, acc);
                acc = MFMA(a1h, bl1, acc);
                acc = MFMA(a1h, bh1, acc);
                if (m16 < 4) {
                    #pragma unroll
                    for (int i = 0; i < 4; ++i)
                        H3[(4 * g + i) * 8 + m16 + 4 * mlp] = acc[i];
                }
            }
        }

        // ---- epilogue: 16 lanes, one edge each (wave-internal LDS, no barrier)
        if (lane < 16) {
            const int e2 = tile * 16 + lane;
            if (e2 < E) {
                const float4 Ai4 = *reinterpret_cast<const float4*>(&H3[lane * 8 + 4]);
                const float4 Ar4 = *reinterpret_cast<const float4*>(&H3[lane * 8 + 0]);
                const float Ai[4] = {Ai4.x, Ai4.y, Ai4.z, Ai4.w};
                const float Ar[4] = {Ar4.x, Ar4.y, Ar4.z, Ar4.w};
                const int r = ei[E + e2];
                #pragma unroll
                for (int t = 0; t < 3; ++t) {
                    float z = bav[t];
                    #pragma unroll
                    for (int j = 0; j < 4; ++j) z += Ai[j] * wav[j * 3 + t];
                    #pragma unroll
                    for (int j = 0; j < 4; ++j) z += Ar[j] * wav[(4 + j) * 3 + t];
                    atomicAdd(aggout + (size_t)stride * (size_t)r + t, tanh_f(z) * PI_F);
                }
            }
        }
    }
}

// ---------------- round-6 scalar fallback (ws too small) ----------------
__device__ __forceinline__ void mlp14_64_64_4(
    const float x[14],
    const float* __restrict__ W1, const float* __restrict__ b1,
    const float* __restrict__ W2, const float* __restrict__ b2,
    const float* __restrict__ W3, const float* __restrict__ b3,
    float A[4])
{
    float h1[64];
    #pragma unroll
    for (int j = 0; j < 64; ++j) h1[j] = b1[j];
    #pragma unroll
    for (int k = 0; k < 14; ++k) {
        const float xk = x[k];
        #pragma unroll
        for (int j = 0; j < 64; ++j) h1[j] += xk * W1[k * 64 + j];
    }
    #pragma unroll
    for (int j = 0; j < 64; ++j) h1[j] = silu_f(h1[j]);
    float h2[64];
    #pragma unroll
    for (int j = 0; j < 64; ++j) h2[j] = b2[j];
    #pragma unroll
    for (int k = 0; k < 64; ++k) {
        const float hk = h1[k];
        #pragma unroll
        for (int j = 0; j < 64; ++j) h2[j] += hk * W2[k * 64 + j];
    }
    #pragma unroll
    for (int j = 0; j < 64; ++j) h2[j] = silu_f(h2[j]);
    float a0 = b3[0], a1 = b3[1], a2 = b3[2], a3 = b3[3];
    #pragma unroll
    for (int k = 0; k < 64; ++k) {
        const float hk = h2[k];
        a0 += hk * W3[k * 4 + 0];
        a1 += hk * W3[k * 4 + 1];
        a2 += hk * W3[k * 4 + 2];
        a3 += hk * W3[k * 4 + 3];
    }
    A[0] = a0; A[1] = a1; A[2] = a2; A[3] = a3;
}

template<int STRIDE>
__global__ __launch_bounds__(256) void qgnn_edge_kernel(
    const float* __restrict__ hr, const float* __restrict__ hi,
    const int* __restrict__ ei,
    const float* __restrict__ npar, const float* __restrict__ epar,
    const float* __restrict__ Wa, const float* __restrict__ ba,
    const float* __restrict__ Wr1, const float* __restrict__ br1,
    const float* __restrict__ Wr2, const float* __restrict__ br2,
    const float* __restrict__ Wr3, const float* __restrict__ br3,
    const float* __restrict__ Wi1, const float* __restrict__ bi1,
    const float* __restrict__ Wi2, const float* __restrict__ bi2,
    const float* __restrict__ Wi3, const float* __restrict__ bi3,
    float* __restrict__ aggout, int E)
{
    const int e = blockIdx.x * blockDim.x + threadIdx.x;
    if (e >= E) return;
    const int s = ei[e];
    const int r = ei[E + e];
    const float ep0 = epar[ei[2 * e + 0]];
    const float ep1 = epar[ei[2 * e + 1]];
    const float4 hrs = *reinterpret_cast<const float4*>(hr + 4 * (size_t)s);
    const float4 hrr = *reinterpret_cast<const float4*>(hr + 4 * (size_t)r);
    const float2 nps = *reinterpret_cast<const float2*>(npar + 2 * (size_t)s);
    const float2 npr = *reinterpret_cast<const float2*>(npar + 2 * (size_t)r);
    float x[14];
    x[0] = hrs.x; x[1] = hrs.y; x[2] = hrs.z; x[3] = hrs.w;
    x[4] = hrr.x; x[5] = hrr.y; x[6] = hrr.z; x[7] = hrr.w;
    x[8] = nps.x; x[9] = nps.y; x[10] = npr.x; x[11] = npr.y;
    x[12] = ep0;  x[13] = ep1;
    float Ar[4];
    mlp14_64_64_4(x, Wr1, br1, Wr2, br2, Wr3, br3, Ar);
    const float4 his = *reinterpret_cast<const float4*>(hi + 4 * (size_t)s);
    const float4 hir = *reinterpret_cast<const float4*>(hi + 4 * (size_t)r);
    x[0] = his.x; x[1] = his.y; x[2] = his.z; x[3] = his.w;
    x[4] = hir.x; x[5] = hir.y; x[6] = hir.z; x[7] = hir.w;
    float Ai[4];
    mlp14_64_64_4(x, Wi1, bi1, Wi2, bi2, Wi3, bi3, Ai);
    #pragma unroll
    for (int t = 0; t < 3; ++t) {
        float z = ba[t];
        #pragma unroll
        for (int j = 0; j < 4; ++j) z += Ai[j] * Wa[j * 3 + t];
        #pragma unroll
        for (int j = 0; j < 4; ++j) z += Ar[j] * Wa[(4 + j) * 3 + t];
        atomicAdd(aggout + (size_t)STRIDE * (size_t)r + t, tanh_f(z) * PI_F);
    }
}

// ---------------- node kernel ----------------
__device__ __forceinline__ float wrap_pi(float v) {
    float rm = fmodf(v + PI_F, TWO_PI_F);
    if (rm < 0.0f) rm += TWO_PI_F;
    return rm - PI_F;
}

template<int STRIDE, bool WRITE_COMPLEX>
__global__ __launch_bounds__(256) void qgnn_node_kernel(
    const float* __restrict__ hr,
    const float* __restrict__ hi,
    float* __restrict__ out, int N)
{
    const int n = blockIdx.x * blockDim.x + threadIdx.x;
    if (n >= N) return;
    const float a = wrap_pi(out[(size_t)STRIDE * n + 0]);
    const float b = wrap_pi(out[(size_t)STRIDE * n + 1]);
    const float c = wrap_pi(out[(size_t)STRIDE * n + 2]);
    const float cb = __cosf(0.5f * b);
    const float sb = __sinf(0.5f * b);
    const float hpc = 0.5f * (a + c);
    const float hmc = 0.5f * (a - c);
    const float cpc = __cosf(hpc), spc = __sinf(hpc);
    const float cmc = __cosf(hmc), smc = __sinf(hmc);
    float Ur[2][2], Ui[2][2];
    Ur[0][0] =  cpc * cb;  Ui[0][0] = -spc * cb;
    Ur[0][1] = -cmc * sb;  Ui[0][1] =  smc * sb;
    Ur[1][0] =  cmc * sb;  Ui[1][0] =  smc * sb;
    Ur[1][1] =  cpc * cb;  Ui[1][1] =  spc * cb;
    const float4 h4r = *reinterpret_cast<const float4*>(hr + 4 * (size_t)n);
    const float4 h4i = *reinterpret_cast<const float4*>(hi + 4 * (size_t)n);
    float Hr[2][2] = {{h4r.x, h4r.y}, {h4r.z, h4r.w}};
    float Hi[2][2] = {{h4i.x, h4i.y}, {h4i.z, h4i.w}};
    float Tr[2][2], Ti[2][2];
    #pragma unroll
    for (int p = 0; p < 2; ++p) {
        #pragma unroll
        for (int j = 0; j < 2; ++j) {
            float tr = 0.0f, ti = 0.0f;
            #pragma unroll
            for (int t = 0; t < 2; ++t) {
                tr += Hr[p][t] * Ur[j][t] + Hi[p][t] * Ui[j][t];
                ti += Hi[p][t] * Ur[j][t] - Hr[p][t] * Ui[j][t];
            }
            Tr[p][j] = tr; Ti[p][j] = ti;
        }
    }
    float orr[2][2], oii[2][2];
    #pragma unroll
    for (int i = 0; i < 2; ++i) {
        #pragma unroll
        for (int j = 0; j < 2; ++j) {
            float xr = 0.0f, xi = 0.0f;
            #pragma unroll
            for (int p = 0; p < 2; ++p) {
                xr += Ur[i][p] * Tr[p][j] - Ui[i][p] * Ti[p][j];
                xi += Ur[i][p] * Ti[p][j] + Ui[i][p] * Tr[p][j];
            }
            orr[i][j] = xr; oii[i][j] = xi;
        }
    }
    if (WRITE_COMPLEX) {
        float4* outv = reinterpret_cast<float4*>(out + (size_t)STRIDE * n);
        outv[0] = make_float4(orr[0][0], oii[0][0], orr[0][1], oii[0][1]);
        outv[1] = make_float4(orr[1][0], oii[1][0], orr[1][1], oii[1][1]);
    } else {
        *reinterpret_cast<float4*>(out + (size_t)STRIDE * n) =
            make_float4(orr[0][0], orr[0][1], orr[1][0], orr[1][1]);
    }
}

extern "C" void kernel_launch(void* const* d_in, const int* in_sizes, int n_in,
                              void* d_out, int out_size, void* d_ws, size_t ws_size,
                              hipStream_t stream) {
    const float* hr   = (const float*)d_in[0];
    const float* hi   = (const float*)d_in[1];
    const int*   ei   = (const int*)  d_in[2];
    const float* npar = (const float*)d_in[3];
    const float* epar = (const float*)d_in[4];
    const float* Wa  = (const float*)d_in[5];
    const float* ba  = (const float*)d_in[6];
    const float* Wr1 = (const float*)d_in[7];
    const float* br1 = (const float*)d_in[8];
    const float* Wr2 = (const float*)d_in[9];
    const float* br2 = (const float*)d_in[10];
    const float* Wr3 = (const float*)d_in[11];
    const float* br3 = (const float*)d_in[12];
    const float* Wi1 = (const float*)d_in[13];
    const float* bi1 = (const float*)d_in[14];
    const float* Wi2 = (const float*)d_in[15];
    const float* bi2 = (const float*)d_in[16];
    const float* Wi3 = (const float*)d_in[17];
    const float* bi3 = (const float*)d_in[18];

    const int N = in_sizes[0] / 4;   // h_i_real is (N,2,2)
    const int E = in_sizes[2] / 2;   // edge_index is (2,E)

    float* out = (float*)d_out;
    const bool cplx = (out_size >= 8 * N);
    const int stride = cplx ? 8 : 4;
    const int total = stride * N;
    qgnn_zero_kernel<<<(total + 255) / 256, 256, 0, stream>>>(out, total);

    const bool use_mfma = (ws_size >= (size_t)WS_BYTES_NEEDED);
    if (use_mfma) {
        qgnn_prep_kernel<<<56, 256, 0, stream>>>(Wr1, Wr2, Wr3, Wi1, Wi2, Wi3,
                                                 (unsigned short*)d_ws);
        const int ntiles = (E + 15) / 16;
        int blocks = (ntiles + NW - 1) / NW;
        if (blocks > 2048) blocks = 2048;
        qgnn_edge_mfma_kernel<<<blocks, 256, 0, stream>>>(
            hr, hi, ei, npar, epar, Wa, ba,
            br1, br2, br3, bi1, bi2, bi3,
            (const unsigned short*)d_ws, out, E, stride);
    } else if (cplx) {
        qgnn_edge_kernel<8><<<(E + 255) / 256, 256, 0, stream>>>(
            hr, hi, ei, npar, epar, Wa, ba,
            Wr1, br1, Wr2, br2, Wr3, br3,
            Wi1, bi1, Wi2, bi2, Wi3, bi3, out, E);
    } else {
        qgnn_edge_kernel<4><<<(E + 255) / 256, 256, 0, stream>>>(
            hr, hi, ei, npar, epar, Wa, ba,
            Wr1, br1, Wr2, br2, Wr3, br3,
            Wi1, bi1, Wi2, bi2, Wi3, bi3, out, E);
    }

    if (cplx) {
        qgnn_node_kernel<8, true><<<(N + 255) / 256, 256, 0, stream>>>(hr, hi, out, N);
    } else {
        qgnn_node_kernel<4, false><<<(N + 255) / 256, 256, 0, stream>>>(hr, hi, out, N);
    }
}

// Round 11
// 339.406 us; speedup vs baseline: 7.6245x; 1.0225x over previous
//
// Round 11: occupancy 2->3 blocks/CU. r10: 68% combined issue, 32% stalls at
// 2 waves/SIMD (LDS 77824 caps blocks). W lo-plane (28KB) moved from LDS to
// global reads (L1-resident: 28KB < 32KB L1, shared by all resident waves,
// per-lane 16B coalesced). New LDS 49152 = 3 blocks/CU. Math unchanged.
#include <hip/hip_runtime.h>

#define PI_F     3.14159265358979323846f
#define TWO_PI_F 6.28318530717958647692f

typedef __attribute__((ext_vector_type(8))) short short8;
typedef __attribute__((ext_vector_type(4))) float f32x4;

__device__ __forceinline__ float fast_rcp(float x) { return __builtin_amdgcn_rcpf(x); }
__device__ __forceinline__ float silu_f(float v) { return v * fast_rcp(1.0f + __expf(-v)); }
__device__ __forceinline__ float tanh_f(float z) {
    float ez = __expf(2.0f * z);
    return 1.0f - 2.0f * fast_rcp(ez + 1.0f);
}

// RNE bf16 helpers (prep kernel only — runs once, accuracy-first)
__device__ __forceinline__ unsigned short f2bf(float f) {
    unsigned u = __float_as_uint(f);
    u += 0x7FFFu + ((u >> 16) & 1u);
    return (unsigned short)(u >> 16);
}
__device__ __forceinline__ float bf2f(unsigned short h) {
    return __uint_as_float(((unsigned)h) << 16);
}

// Truncation split (hot path): hi = trunc16(v), lo = trunc16(v - hi). 5 VALU.
__device__ __forceinline__ void split_trunc(float v, unsigned short& h, unsigned short& l) {
    const unsigned u = __float_as_uint(v);
    const float hf = __uint_as_float(u & 0xFFFF0000u);
    h = (unsigned short)(u >> 16);
    l = (unsigned short)(__float_as_uint(v - hf) >> 16);
}

// ---------------- prep: fragment-ordered bf16 hi/lo weight planes ----------
// Layout (validated r8-r10): per MLP (u16): L1 [0,2048) KT=1 NT=4; L2
// [2048,6144) KT=2 NT=4; L3 [6144,7168) KT=2 NT=1. MLP i at +7168.
// hi plane [0,14336), lo plane [14336,28672).
// Frag elem ((kt*NT+nt)*64+lane)*8+j = W[kt*32+8*(lane>>4)+j][nt*16+(lane&15)].
#define WS_U16_TOTAL 28672
#define WS_BYTES_NEEDED (WS_U16_TOTAL * 2)
#define W_HI_U16 14336

__global__ __launch_bounds__(256) void qgnn_prep_kernel(
    const float* __restrict__ Wr1, const float* __restrict__ Wr2, const float* __restrict__ Wr3,
    const float* __restrict__ Wi1, const float* __restrict__ Wi2, const float* __restrict__ Wi3,
    unsigned short* __restrict__ wsu)
{
    int idx = blockIdx.x * 256 + threadIdx.x;
    if (idx >= 14336) return;
    int rel = idx;
    int half = (rel >= 7168);
    if (half) rel -= 7168;
    const float* W; int base, NT, Kr, Nr;
    if (rel < 2048)      { W = half ? Wi1 : Wr1; base = 0;    NT = 4; Kr = 14; Nr = 64; }
    else if (rel < 6144) { W = half ? Wi2 : Wr2; base = 2048; NT = 4; Kr = 64; Nr = 64; }
    else                 { W = half ? Wi3 : Wr3; base = 6144; NT = 1; Kr = 64; Nr = 4;  }
    int f = rel - base;
    int frag = f >> 9, rem = f & 511;
    int l = rem >> 3, j = rem & 7;
    int nt = frag % NT, kt = frag / NT;
    int k = kt * 32 + ((l >> 4) << 3) + j;
    int n = nt * 16 + (l & 15);
    float v = (k < Kr && n < Nr) ? W[k * Nr + n] : 0.0f;
    unsigned short hi = f2bf(v);
    unsigned short lo = f2bf(v - bf2f(hi));
    wsu[idx] = hi;
    wsu[14336 + idx] = lo;
}

__global__ __launch_bounds__(256) void qgnn_zero_kernel(float* __restrict__ p, int n) {
    const int i = blockIdx.x * blockDim.x + threadIdx.x;
    if (i < n) p[i] = 0.0f;
}

#define MFMA(a, b, c) __builtin_amdgcn_mfma_f32_16x16x32_bf16((a), (b), (c), 0, 0, 0)
#define NW 4   // waves per block

__global__ __launch_bounds__(256) void qgnn_edge_mfma_kernel(
    const float* __restrict__ hr, const float* __restrict__ hi_,
    const int* __restrict__ ei,
    const float* __restrict__ npar, const float* __restrict__ epar,
    const float* __restrict__ Wa, const float* __restrict__ ba,
    const float* __restrict__ br1, const float* __restrict__ br2, const float* __restrict__ br3,
    const float* __restrict__ bi1, const float* __restrict__ bi2, const float* __restrict__ bi3,
    const unsigned short* __restrict__ wsu,
    float* __restrict__ aggout, int E, int stride)
{
    __shared__ __align__(16) unsigned short sW[W_HI_U16];          // 28672 B (hi plane)
    __shared__ __align__(16) unsigned short sHh[NW][16 * 72];      // 4x2304 B
    __shared__ __align__(16) unsigned short sHl[NW][16 * 72];      // 4x2304 B
    __shared__ __align__(16) float sH3[NW][16 * 8];                // 4x512 B
    // total 49152 B -> 3 blocks/CU

    // ---- stage hi-plane weights once (the only barrier in this kernel) ----
    for (int o = threadIdx.x * 8; o < W_HI_U16; o += 256 * 8)
        *reinterpret_cast<uint4*>(sW + o) = *reinterpret_cast<const uint4*>(wsu + o);
    __syncthreads();

    const int tid = threadIdx.x, w = tid >> 6, lane = tid & 63;
    const int m16 = lane & 15, g = lane >> 4;
    unsigned short* Hh = sHh[w];
    unsigned short* Hl = sHl[w];
    float* H3 = sH3[w];

    // ---- per-lane constants preloaded once ----
    float br1v[4], br2v[4], bi1v[4], bi2v[4];
    #pragma unroll
    for (int q = 0; q < 4; ++q) {
        br1v[q] = br1[q * 16 + m16];
        br2v[q] = br2[q * 16 + m16];
        bi1v[q] = bi1[q * 16 + m16];
        bi2v[q] = bi2[q * 16 + m16];
    }
    const float br3v = (m16 < 4) ? br3[m16] : 0.0f;
    const float bi3v = (m16 < 4) ? bi3[m16] : 0.0f;
    float wav[24], bav[3];
    #pragma unroll
    for (int q = 0; q < 24; ++q) wav[q] = Wa[q];
    #pragma unroll
    for (int q = 0; q < 3; ++q) bav[q] = ba[q];

    const int ntiles = (E + 15) >> 4;
    for (int tile = blockIdx.x * NW + w; tile < ntiles; tile += gridDim.x * NW) {
        const int em = tile * 16 + m16;
        const bool valid = (em < E);

        // ---- gather X straight into registers (no LDS, no barrier) ----
        float f0[8], f1[8];
        #pragma unroll
        for (int j = 0; j < 8; ++j) { f0[j] = 0.0f; f1[j] = 0.0f; }
        if (valid && g < 2) {
            const int s = ei[em], r = ei[E + em];
            if (g == 0) {
                const float4 a = *reinterpret_cast<const float4*>(hr  + 4 * (size_t)s);
                const float4 b = *reinterpret_cast<const float4*>(hr  + 4 * (size_t)r);
                const float4 c = *reinterpret_cast<const float4*>(hi_ + 4 * (size_t)s);
                const float4 d = *reinterpret_cast<const float4*>(hi_ + 4 * (size_t)r);
                f0[0] = a.x; f0[1] = a.y; f0[2] = a.z; f0[3] = a.w;
                f0[4] = b.x; f0[5] = b.y; f0[6] = b.z; f0[7] = b.w;
                f1[0] = c.x; f1[1] = c.y; f1[2] = c.z; f1[3] = c.w;
                f1[4] = d.x; f1[5] = d.y; f1[6] = d.z; f1[7] = d.w;
            } else {
                const float2 n0 = *reinterpret_cast<const float2*>(npar + 2 * (size_t)s);
                const float2 n1 = *reinterpret_cast<const float2*>(npar + 2 * (size_t)r);
                const float e0 = epar[ei[2 * em + 0]];
                const float e1 = epar[ei[2 * em + 1]];
                f0[0] = n0.x; f0[1] = n0.y; f0[2] = n1.x; f0[3] = n1.y;
                f0[4] = e0;   f0[5] = e1;
                #pragma unroll
                for (int j = 0; j < 6; ++j) f1[j] = f0[j];
            }
        }
        short8 xh0, xl0, xh1, xl1;
        #pragma unroll
        for (int j = 0; j < 8; ++j) {
            unsigned short h, l;
            split_trunc(f0[j], h, l);
            xh0[j] = (short)h; xl0[j] = (short)l;
            split_trunc(f1[j], h, l);
            xh1[j] = (short)h; xl1[j] = (short)l;
        }

        #pragma unroll 1
        for (int mlp = 0; mlp < 2; ++mlp) {
            const unsigned short* wh  = sW + mlp * 7168;                    // LDS (hi)
            const unsigned short* wlg = wsu + W_HI_U16 + mlp * 7168;       // global (lo, L1-hot)
            const short8 ah = mlp ? xh1 : xh0;
            const short8 al = mlp ? xl1 : xl0;

            // ---------- Layer 1: (16x32) @ (32x64) ----------
            #pragma unroll
            for (int nt = 0; nt < 4; ++nt) {
                const float bv = mlp ? bi1v[nt] : br1v[nt];
                f32x4 acc = {bv, bv, bv, bv};
                const short8 bh = *reinterpret_cast<const short8*>(&wh[(nt * 64 + lane) * 8]);
                const short8 bl = *reinterpret_cast<const short8*>(&wlg[(nt * 64 + lane) * 8]);
                acc = MFMA(al, bh, acc);
                acc = MFMA(ah, bl, acc);
                acc = MFMA(ah, bh, acc);
                #pragma unroll
                for (int i = 0; i < 4; ++i) {
                    const float hv = silu_f(acc[i]);
                    const int row = 4 * g + i, col = nt * 16 + m16;
                    unsigned short hh, hl;
                    split_trunc(hv, hh, hl);
                    Hh[row * 72 + col] = hh;
                    Hl[row * 72 + col] = hl;
                }
            }

            // ---------- Layer 2: (16x64) @ (64x64) ----------
            {
                const short8 a0h = *reinterpret_cast<const short8*>(&Hh[m16 * 72 + 8 * g]);
                const short8 a0l = *reinterpret_cast<const short8*>(&Hl[m16 * 72 + 8 * g]);
                const short8 a1h = *reinterpret_cast<const short8*>(&Hh[m16 * 72 + 32 + 8 * g]);
                const short8 a1l = *reinterpret_cast<const short8*>(&Hl[m16 * 72 + 32 + 8 * g]);
                #pragma unroll
                for (int nt = 0; nt < 4; ++nt) {
                    const float bv = mlp ? bi2v[nt] : br2v[nt];
                    f32x4 acc = {bv, bv, bv, bv};
                    const short8 bh0 = *reinterpret_cast<const short8*>(&wh[2048 + ((0 * 4 + nt) * 64 + lane) * 8]);
                    const short8 bl0 = *reinterpret_cast<const short8*>(&wlg[2048 + ((0 * 4 + nt) * 64 + lane) * 8]);
                    const short8 bh1 = *reinterpret_cast<const short8*>(&wh[2048 + ((1 * 4 + nt) * 64 + lane) * 8]);
                    const short8 bl1 = *reinterpret_cast<const short8*>(&wlg[2048 + ((1 * 4 + nt) * 64 + lane) * 8]);
                    acc = MFMA(a0l, bh0, acc);
                    acc = MFMA(a0h, bl0, acc);
                    acc = MFMA(a0h, bh0, acc);
                    acc = MFMA(a1l, bh1, acc);
                    acc = MFMA(a1h, bl1, acc);
                    acc = MFMA(a1h, bh1, acc);
                    #pragma unroll
                    for (int i = 0; i < 4; ++i) {
                        const float hv = silu_f(acc[i]);
                        const int row = 4 * g + i, col = nt * 16 + m16;
                        unsigned short hh, hl;
                        split_trunc(hv, hh, hl);
                        Hh[row * 72 + col] = hh;     // overwrite ok: a-frags already in regs
                        Hl[row * 72 + col] = hl;
                    }
                }
            }

            // ---------- Layer 3: (16x64) @ (64x16), 4 valid cols ----------
            {
                const short8 a0h = *reinterpret_cast<const short8*>(&Hh[m16 * 72 + 8 * g]);
                const short8 a0l = *reinterpret_cast<const short8*>(&Hl[m16 * 72 + 8 * g]);
                const short8 a1h = *reinterpret_cast<const short8*>(&Hh[m16 * 72 + 32 + 8 * g]);
                const short8 a1l = *reinterpret_cast<const short8*>(&Hl[m16 * 72 + 32 + 8 * g]);
                const float bv = mlp ? bi3v : br3v;
                f32x4 acc = {bv, bv, bv, bv};
                const short8 bh0 = *reinterpret_cast<const short8*>(&wh[6144 + (0 * 64 + lane) * 8]);
                const short8 bl0 = *reinterpret_cast<const short8*>(&wlg[6144 + (0 * 64 + lane) * 8]);
                const short8 bh1 = *reinterpret_cast<const short8*>(&wh[6144 + (1 * 64 + lane) * 8]);
                const short8 bl1 = *reinterpret_cast<const short8*>(&wlg[6144 + (1 * 64 + lane) * 8]);
                acc = MFMA(a0l, bh0, acc);
                acc = MFMA(a0h, bl0, acc);
                acc = MFMA(a0h, bh0, acc);
                acc = MFMA(a1l, bh1, acc);
                acc = MFMA(a1h, bl1, acc);
                acc = MFMA(a1h, bh1, acc);
                if (m16 < 4) {
                    #pragma unroll
                    for (int i = 0; i < 4; ++i)
                        H3[(4 * g + i) * 8 + m16 + 4 * mlp] = acc[i];
                }
            }
        }

        // ---- epilogue: 16 lanes, one edge each (wave-internal LDS, no barrier)
        if (lane < 16) {
            const int e2 = tile * 16 + lane;
            if (e2 < E) {
                const float4 Ai4 = *reinterpret_cast<const float4*>(&H3[lane * 8 + 4]);
                const float4 Ar4 = *reinterpret_cast<const float4*>(&H3[lane * 8 + 0]);
                const float Ai[4] = {Ai4.x, Ai4.y, Ai4.z, Ai4.w};
                const float Ar[4] = {Ar4.x, Ar4.y, Ar4.z, Ar4.w};
                const int r = ei[E + e2];
                #pragma unroll
                for (int t = 0; t < 3; ++t) {
                    float z = bav[t];
                    #pragma unroll
                    for (int j = 0; j < 4; ++j) z += Ai[j] * wav[j * 3 + t];
                    #pragma unroll
                    for (int j = 0; j < 4; ++j) z += Ar[j] * wav[(4 + j) * 3 + t];
                    atomicAdd(aggout + (size_t)stride * (size_t)r + t, tanh_f(z) * PI_F);
                }
            }
        }
    }
}

// ---------------- round-6 scalar fallback (ws too small) ----------------
__device__ __forceinline__ void mlp14_64_64_4(
    const float x[14],
    const float* __restrict__ W1, const float* __restrict__ b1,
    const float* __restrict__ W2, const float* __restrict__ b2,
    const float* __restrict__ W3, const float* __restrict__ b3,
    float A[4])
{
    float h1[64];
    #pragma unroll
    for (int j = 0; j < 64; ++j) h1[j] = b1[j];
    #pragma unroll
    for (int k = 0; k < 14; ++k) {
        const float xk = x[k];
        #pragma unroll
        for (int j = 0; j < 64; ++j) h1[j] += xk * W1[k * 64 + j];
    }
    #pragma unroll
    for (int j = 0; j < 64; ++j) h1[j] = silu_f(h1[j]);
    float h2[64];
    #pragma unroll
    for (int j = 0; j < 64; ++j) h2[j] = b2[j];
    #pragma unroll
    for (int k = 0; k < 64; ++k) {
        const float hk = h1[k];
        #pragma unroll
        for (int j = 0; j < 64; ++j) h2[j] += hk * W2[k * 64 + j];
    }
    #pragma unroll
    for (int j = 0; j < 64; ++j) h2[j] = silu_f(h2[j]);
    float a0 = b3[0], a1 = b3[1], a2 = b3[2], a3 = b3[3];
    #pragma unroll
    for (int k = 0; k < 64; ++k) {
        const float hk = h2[k];
        a0 += hk * W3[k * 4 + 0];
        a1 += hk * W3[k * 4 + 1];
        a2 += hk * W3[k * 4 + 2];
        a3 += hk * W3[k * 4 + 3];
    }
    A[0] = a0; A[1] = a1; A[2] = a2; A[3] = a3;
}

template<int STRIDE>
__global__ __launch_bounds__(256) void qgnn_edge_kernel(
    const float* __restrict__ hr, const float* __restrict__ hi,
    const int* __restrict__ ei,
    const float* __restrict__ npar, const float* __restrict__ epar,
    const float* __restrict__ Wa, const float* __restrict__ ba,
    const float* __restrict__ Wr1, const float* __restrict__ br1,
    const float* __restrict__ Wr2, const float* __restrict__ br2,
    const float* __restrict__ Wr3, const float* __restrict__ br3,
    const float* __restrict__ Wi1, const float* __restrict__ bi1,
    const float* __restrict__ Wi2, const float* __restrict__ bi2,
    const float* __restrict__ Wi3, const float* __restrict__ bi3,
    float* __restrict__ aggout, int E)
{
    const int e = blockIdx.x * blockDim.x + threadIdx.x;
    if (e >= E) return;
    const int s = ei[e];
    const int r = ei[E + e];
    const float ep0 = epar[ei[2 * e + 0]];
    const float ep1 = epar[ei[2 * e + 1]];
    const float4 hrs = *reinterpret_cast<const float4*>(hr + 4 * (size_t)s);
    const float4 hrr = *reinterpret_cast<const float4*>(hr + 4 * (size_t)r);
    const float2 nps = *reinterpret_cast<const float2*>(npar + 2 * (size_t)s);
    const float2 npr = *reinterpret_cast<const float2*>(npar + 2 * (size_t)r);
    float x[14];
    x[0] = hrs.x; x[1] = hrs.y; x[2] = hrs.z; x[3] = hrs.w;
    x[4] = hrr.x; x[5] = hrr.y; x[6] = hrr.z; x[7] = hrr.w;
    x[8] = nps.x; x[9] = nps.y; x[10] = npr.x; x[11] = npr.y;
    x[12] = ep0;  x[13] = ep1;
    float Ar[4];
    mlp14_64_64_4(x, Wr1, br1, Wr2, br2, Wr3, br3, Ar);
    const float4 his = *reinterpret_cast<const float4*>(hi + 4 * (size_t)s);
    const float4 hir = *reinterpret_cast<const float4*>(hi + 4 * (size_t)r);
    x[0] = his.x; x[1] = his.y; x[2] = his.z; x[3] = his.w;
    x[4] = hir.x; x[5] = hir.y; x[6] = hir.z; x[7] = hir.w;
    float Ai[4];
    mlp14_64_64_4(x, Wi1, bi1, Wi2, bi2, Wi3, bi3, Ai);
    #pragma unroll
    for (int t = 0; t < 3; ++t) {
        float z = ba[t];
        #pragma unroll
        for (int j = 0; j < 4; ++j) z += Ai[j] * Wa[j * 3 + t];
        #pragma unroll
        for (int j = 0; j < 4; ++j) z += Ar[j] * Wa[(4 + j) * 3 + t];
        atomicAdd(aggout + (size_t)STRIDE * (size_t)r + t, tanh_f(z) * PI_F);
    }
}

// ---------------- node kernel ----------------
__device__ __forceinline__ float wrap_pi(float v) {
    float rm = fmodf(v + PI_F, TWO_PI_F);
    if (rm < 0.0f) rm += TWO_PI_F;
    return rm - PI_F;
}

template<int STRIDE, bool WRITE_COMPLEX>
__global__ __launch_bounds__(256) void qgnn_node_kernel(
    const float* __restrict__ hr,
    const float* __restrict__ hi,
    float* __restrict__ out, int N)
{
    const int n = blockIdx.x * blockDim.x + threadIdx.x;
    if (n >= N) return;
    const float a = wrap_pi(out[(size_t)STRIDE * n + 0]);
    const float b = wrap_pi(out[(size_t)STRIDE * n + 1]);
    const float c = wrap_pi(out[(size_t)STRIDE * n + 2]);
    const float cb = __cosf(0.5f * b);
    const float sb = __sinf(0.5f * b);
    const float hpc = 0.5f * (a + c);
    const float hmc = 0.5f * (a - c);
    const float cpc = __cosf(hpc), spc = __sinf(hpc);
    const float cmc = __cosf(hmc), smc = __sinf(hmc);
    float Ur[2][2], Ui[2][2];
    Ur[0][0] =  cpc * cb;  Ui[0][0] = -spc * cb;
    Ur[0][1] = -cmc * sb;  Ui[0][1] =  smc * sb;
    Ur[1][0] =  cmc * sb;  Ui[1][0] =  smc * sb;
    Ur[1][1] =  cpc * cb;  Ui[1][1] =  spc * cb;
    const float4 h4r = *reinterpret_cast<const float4*>(hr + 4 * (size_t)n);
    const float4 h4i = *reinterpret_cast<const float4*>(hi + 4 * (size_t)n);
    float Hr[2][2] = {{h4r.x, h4r.y}, {h4r.z, h4r.w}};
    float Hi[2][2] = {{h4i.x, h4i.y}, {h4i.z, h4i.w}};
    float Tr[2][2], Ti[2][2];
    #pragma unroll
    for (int p = 0; p < 2; ++p) {
        #pragma unroll
        for (int j = 0; j < 2; ++j) {
            float tr = 0.0f, ti = 0.0f;
            #pragma unroll
            for (int t = 0; t < 2; ++t) {
                tr += Hr[p][t] * Ur[j][t] + Hi[p][t] * Ui[j][t];
                ti += Hi[p][t] * Ur[j][t] - Hr[p][t] * Ui[j][t];
            }
            Tr[p][j] = tr; Ti[p][j] = ti;
        }
    }
    float orr[2][2], oii[2][2];
    #pragma unroll
    for (int i = 0; i < 2; ++i) {
        #pragma unroll
        for (int j = 0; j < 2; ++j) {
            float xr = 0.0f, xi = 0.0f;
            #pragma unroll
            for (int p = 0; p < 2; ++p) {
                xr += Ur[i][p] * Tr[p][j] - Ui[i][p] * Ti[p][j];
                xi += Ur[i][p] * Ti[p][j] + Ui[i][p] * Tr[p][j];
            }
            orr[i][j] = xr; oii[i][j] = xi;
        }
    }
    if (WRITE_COMPLEX) {
        float4* outv = reinterpret_cast<float4*>(out + (size_t)STRIDE * n);
        outv[0] = make_float4(orr[0][0], oii[0][0], orr[0][1], oii[0][1]);
        outv[1] = make_float4(orr[1][0], oii[1][0], orr[1][1], oii[1][1]);
    } else {
        *reinterpret_cast<float4*>(out + (size_t)STRIDE * n) =
            make_float4(orr[0][0], orr[0][1], orr[1][0], orr[1][1]);
    }
}

extern "C" void kernel_launch(void* const* d_in, const int* in_sizes, int n_in,
                              void* d_out, int out_size, void* d_ws, size_t ws_size,
                              hipStream_t stream) {
    const float* hr   = (const float*)d_in[0];
    const float* hi   = (const float*)d_in[1];
    const int*   ei   = (const int*)  d_in[2];
    const float* npar = (const float*)d_in[3];
    const float* epar = (const float*)d_in[4];
    const float* Wa  = (const float*)d_in[5];
    const float* ba  = (const float*)d_in[6];
    const float* Wr1 = (const float*)d_in[7];
    const float* br1 = (const float*)d_in[8];
    const float* Wr2 = (const float*)d_in[9];
    const float* br2 = (const float*)d_in[10];
    const float* Wr3 = (const float*)d_in[11];
    const float* br3 = (const float*)d_in[12];
    const float* Wi1 = (const float*)d_in[13];
    const float* bi1 = (const float*)d_in[14];
    const float* Wi2 = (const float*)d_in[15];
    const float* bi2 = (const float*)d_in[16];
    const float* Wi3 = (const float*)d_in[17];
    const float* bi3 = (const float*)d_in[18];

    const int N = in_sizes[0] / 4;   // h_i_real is (N,2,2)
    const int E = in_sizes[2] / 2;   // edge_index is (2,E)

    float* out = (float*)d_out;
    const bool cplx = (out_size >= 8 * N);
    const int stride = cplx ? 8 : 4;
    const int total = stride * N;
    qgnn_zero_kernel<<<(total + 255) / 256, 256, 0, stream>>>(out, total);

    const bool use_mfma = (ws_size >= (size_t)WS_BYTES_NEEDED);
    if (use_mfma) {
        qgnn_prep_kernel<<<56, 256, 0, stream>>>(Wr1, Wr2, Wr3, Wi1, Wi2, Wi3,
                                                 (unsigned short*)d_ws);
        const int ntiles = (E + 15) / 16;
        int blocks = (ntiles + NW - 1) / NW;
        if (blocks > 3072) blocks = 3072;   // 3 blocks/CU x 256 CU x (grid-stride)
        qgnn_edge_mfma_kernel<<<blocks, 256, 0, stream>>>(
            hr, hi, ei, npar, epar, Wa, ba,
            br1, br2, br3, bi1, bi2, bi3,
            (const unsigned short*)d_ws, out, E, stride);
    } else if (cplx) {
        qgnn_edge_kernel<8><<<(E + 255) / 256, 256, 0, stream>>>(
            hr, hi, ei, npar, epar, Wa, ba,
            Wr1, br1, Wr2, br2, Wr3, br3,
            Wi1, bi1, Wi2, bi2, Wi3, bi3, out, E);
    } else {
        qgnn_edge_kernel<4><<<(E + 255) / 256, 256, 0, stream>>>(
            hr, hi, ei, npar, epar, Wa, ba,
            Wr1, br1, Wr2, br2, Wr3, br3,
            Wi1, bi1, Wi2, bi2, Wi3, bi3, out, E);
    }

    if (cplx) {
        qgnn_node_kernel<8, true><<<(N + 255) / 256, 256, 0, stream>>>(hr, hi, out, N);
    } else {
        qgnn_node_kernel<4, false><<<(N + 255) / 256, 256, 0, stream>>>(hr, hi, out, N);
    }
}